// Round 10
// baseline (127.220 us; speedup 1.0000x reference)
//
#include <hip/hip_runtime.h>
#include <stdint.h>

typedef short short8 __attribute__((ext_vector_type(8)));
typedef short short4v __attribute__((ext_vector_type(4)));
typedef float f32x4 __attribute__((ext_vector_type(4)));
typedef unsigned int u32x2 __attribute__((ext_vector_type(2)));
typedef unsigned int u32x4 __attribute__((ext_vector_type(4)));
typedef unsigned short u16;
typedef unsigned int u32;

#define T_ 2048
#define QK_SCALE 0.180336878f   // 0.125 * log2(e): softmax in log2 domain

__device__ inline u16 f2bf(float f) {
  unsigned u = __builtin_bit_cast(unsigned, f);
  u += 0x7fffu + ((u >> 16) & 1u);   // RNE; inputs finite
  return (u16)(u >> 16);
}

__device__ inline float bf2f(u16 v) {
  return __builtin_bit_cast(float, (u32)v << 16);
}

__device__ inline u32 cvt_pk_bf16(float lo, float hi) {
  u32 r;
  asm("v_cvt_pk_bf16_f32 %0, %1, %2" : "=v"(r) : "v"(lo), "v"(hi));
  return r;
}

__device__ inline f32x4 mfma_bf16(short8 a, short8 b, f32x4 c) {
  return __builtin_amdgcn_mfma_f32_16x16x32_bf16(a, b, c, 0, 0, 0);
}

// async global->LDS, 16B per lane; lds base must be wave-uniform
__device__ inline void gload16(const u16* g, u16* l) {
  __builtin_amdgcn_global_load_lds(
      (const __attribute__((address_space(1))) void*)g,
      (__attribute__((address_space(3))) void*)l, 16, 0, 0);
}

// ---------------- fused prep: convert x + transpose-convert both weights ----------------

__device__ inline void tile_transpose(const float* __restrict__ W, u16* __restrict__ Wt,
                                      int R, int Ccols, int c0, int r0, int t,
                                      float (*tile)[33]) {
  int tr = t >> 3, tc = (t & 7) * 4;
  float4 v = *(const float4*)&W[(size_t)(r0 + tr) * Ccols + c0 + tc];
  tile[tr][tc + 0] = v.x; tile[tr][tc + 1] = v.y;
  tile[tr][tc + 2] = v.z; tile[tr][tc + 3] = v.w;
  __syncthreads();
  short4v o;
#pragma unroll
  for (int i = 0; i < 4; ++i) o[i] = (short)f2bf(tile[tc + i][tr]);
  *(short4v*)&Wt[(size_t)(c0 + tr) * R + r0 + tc] = o;
}

__global__ __launch_bounds__(256) void prep_kernel(const float* __restrict__ x,
                                                   const float* __restrict__ Wqkv,
                                                   const float* __restrict__ Wproj,
                                                   u16* __restrict__ xb,
                                                   u16* __restrict__ wqkvT,
                                                   u16* __restrict__ wprojT) {
  __shared__ float tile[32][33];
  int bid = blockIdx.x, t = threadIdx.x;
  if (bid < 3072) {
    int i = (bid * 256 + t) * 4;
    float4 v = *(const float4*)&x[i];
    short4v o;
    o[0] = (short)f2bf(v.x); o[1] = (short)f2bf(v.y);
    o[2] = (short)f2bf(v.z); o[3] = (short)f2bf(v.w);
    *(short4v*)&xb[i] = o;
  } else if (bid < 3072 + 1728) {
    int t2 = bid - 3072;
    tile_transpose(Wqkv, wqkvT, 768, 2304, (t2 % 72) * 32, (t2 / 72) * 32, t, tile);
  } else {
    int t3 = bid - 4800;
    tile_transpose(Wproj, wprojT, 768, 768, (t3 % 24) * 32, (t3 / 24) * 32, t, tile);
  }
}

// ---------------- MTILE x 128 GEMM (gload_lds w16 + XOR swizzle + XCD chunking) ----------------

template <int MODE, int MTILE>
__global__ __launch_bounds__(256) void gemm_kernel(const u16* __restrict__ A,
                                                   const u16* __restrict__ Bt,
                                                   const float* __restrict__ bias,
                                                   u16* __restrict__ qb,
                                                   u16* __restrict__ kb,
                                                   u16* __restrict__ vpb,
                                                   float* __restrict__ out) {
  constexpr int MF = MTILE / 32;            // m-fragments per wave
  __shared__ u16 S[MTILE * 64 + 8192];      // As | Bs (reused as transpose buf)
  u16* As = S;
  u16* Bs = S + MTILE * 64;
  int tid = threadIdx.x, w = tid >> 6, l = tid & 63, lg = l >> 4, lr = l & 15;
  int nwg = gridDim.x * gridDim.y;
  int hw = blockIdx.y * gridDim.x + blockIdx.x;
  int logical = (hw & 7) * (nwg >> 3) + (hw >> 3);
  int n0 = (logical % gridDim.x) * 128, m0 = (logical / gridDim.x) * MTILE;
  int wm = (w >> 1) * (MTILE / 2), wn = (w & 1) * 64;
  f32x4 acc[MF][4] = {};
  int rsub = l >> 3;
  int sc = ((l & 7) ^ rsub) * 8;
  for (int kt = 0; kt < 12; ++kt) {
    int k0 = kt * 64;
    __syncthreads();
#pragma unroll
    for (int j = 0; j < MF; ++j) {
      int row = w * (MTILE / 4) + j * 8 + rsub;
      gload16(&A[(size_t)(m0 + row) * 768 + k0 + sc], &As[(w * MF + j) * 512]);
    }
#pragma unroll
    for (int j = 0; j < 4; ++j) {
      int row = w * 32 + j * 8 + rsub;
      gload16(&Bt[(size_t)(n0 + row) * 768 + k0 + sc], &Bs[(w * 4 + j) * 512]);
    }
    __syncthreads();
    short8 a[MF][2], b[4][2];
#pragma unroll
    for (int h = 0; h < 2; ++h) {
#pragma unroll
      for (int mf = 0; mf < MF; ++mf) {
        int cw = ((h * 4 + lg) ^ (lr & 7)) * 8;
        a[mf][h] = *(const short8*)&As[(wm + mf * 16 + lr) * 64 + cw];
      }
#pragma unroll
      for (int nf = 0; nf < 4; ++nf) {
        int cw = ((h * 4 + lg) ^ (lr & 7)) * 8;
        b[nf][h] = *(const short8*)&Bs[(wn + nf * 16 + lr) * 64 + cw];
      }
    }
#pragma unroll
    for (int h = 0; h < 2; ++h)
#pragma unroll
      for (int mf = 0; mf < MF; ++mf)
#pragma unroll
        for (int nf = 0; nf < 4; ++nf)
          acc[mf][nf] = mfma_bf16(a[mf][h], b[nf][h], acc[mf][nf]);
  }

  if constexpr (MODE == 0) {
    int sec = (n0 >= 1536) ? 2 : (n0 >= 768 ? 1 : 0);
    int ncol0 = n0 - sec * 768;
    if (sec < 2) {
#pragma unroll
      for (int nf = 0; nf < 4; ++nf) {
        int nn = wn + nf * 16 + lr;
        float bv = bias[n0 + nn];
        int c = ncol0 + nn;
        int hh = c >> 6, d = c & 63;
#pragma unroll
        for (int mf = 0; mf < MF; ++mf)
#pragma unroll
          for (int rr = 0; rr < 4; ++rr) {
            int m = m0 + wm + mf * 16 + 4 * lg + rr;
            int bb = m >> 11, tt = m & 2047;
            int bh = bb * 12 + hh;
            float v = acc[mf][nf][rr] + bv;
            if (sec == 0) qb[((size_t)bh * T_ + tt) * 64 + d] = f2bf(v * QK_SCALE);
            else          kb[((size_t)bh * T_ + tt) * 64 + d] = f2bf(v);
          }
      }
    } else {
      // V^T: transpose in LDS (p5 key-permutation folded into column), coalesced rows out.
      __syncthreads();
#pragma unroll
      for (int nf = 0; nf < 4; ++nf) {
        int row = wn + nf * 16 + lr;
        float bv = bias[n0 + row];
        int swz = (row & 7) << 3;
#pragma unroll
        for (int mf = 0; mf < MF; ++mf) {
          int pcol0 = wm + (mf >> 1) * 32 + 8 * lg + 4 * (mf & 1);
          u32x2 pk;
          pk[0] = cvt_pk_bf16(acc[mf][nf][0] + bv, acc[mf][nf][1] + bv);
          pk[1] = cvt_pk_bf16(acc[mf][nf][2] + bv, acc[mf][nf][3] + bv);
          *(u32x2*)&S[row * MTILE + (pcol0 ^ swz)] = pk;
        }
      }
      __syncthreads();
      constexpr int CPT = MTILE / 2;
      int rowo = tid >> 1, half = tid & 1;
      int c = ncol0 + rowo;
      int d = c & 63, hh = c >> 6;
      int bh = (m0 >> 11) * 12 + hh;
      u16* dst = vpb + ((size_t)bh * 64 + d) * T_ + (m0 & 2047) + half * CPT;
      int swzo = (rowo & 7) << 3;
#pragma unroll
      for (int i = 0; i < CPT / 8; ++i) {
        int col = half * CPT + i * 8;
        uint4 v = *(const uint4*)&S[rowo * MTILE + (col ^ swzo)];
        *(uint4*)&dst[i * 8] = v;
      }
    }
  } else {
#pragma unroll
    for (int nf = 0; nf < 4; ++nf) {
      int n = n0 + wn + nf * 16 + lr;
      float bv = bias[n];
#pragma unroll
      for (int mf = 0; mf < MF; ++mf)
#pragma unroll
        for (int rr = 0; rr < 4; ++rr) {
          int m = m0 + wm + mf * 16 + 4 * lg + rr;
          out[(size_t)m * 768 + n] = acc[mf][nf][rr] + bv;
        }
    }
  }
}

// ---------------- split-K flash attention v2 (flat, per-wave units, no barriers) ----------------
// No-max softmax => partials over disjoint key chunks combine by ADDITION.
// Unit = (head, 32-q strip s, chunk c). Trivial bijective map; all 2304 units
// co-resident (576 blocks x 4 waves = 9 waves/CU) so ordering is irrelevant.
// s<32: single chunk, direct O write. s>=32: c=0 keys [0,1024), c=1 keys [1024, ...).

__global__ __launch_bounds__(256, 2) void attn_split_kernel(const u16* __restrict__ Q,
                                                            const u16* __restrict__ K,
                                                            const u16* __restrict__ Vp,
                                                            u16* __restrict__ O,
                                                            u16* __restrict__ Pp,
                                                            float* __restrict__ Lp) {
  __shared__ u16 sh[4 * 2304];          // per-wave [32][72] transpose buffers
  int tid = threadIdx.x, w = tid >> 6, l = tid & 63, lg = l >> 4, lr = l & 15;
  int unit = blockIdx.x * 4 + w;
  int head = unit % 24;
  int v = unit / 24;                    // 0..95
  int s, c;
  if (v < 32) { s = v; c = 0; }
  else        { int w2 = v - 32; s = 32 + (w2 >> 1); c = w2 & 1; }
  int b = head / 12, h = head % 12;
  int q0 = s * 32;
  const u16* Qb = Q + (size_t)head * T_ * 64;
  const u16* Kb = K + (size_t)head * T_ * 64;
  const u16* Vb = Vp + (size_t)head * 64 * T_;

  short8 qf[2][2];
#pragma unroll
  for (int qc = 0; qc < 2; ++qc)
#pragma unroll
    for (int hh = 0; hh < 2; ++hh)
      qf[qc][hh] = *(const short8*)&Qb[(size_t)(q0 + qc * 16 + lr) * 64 + hh * 32 + 8 * lg];

  f32x4 ao[4][2] = {};
  float lrow[2] = {0.f, 0.f};

  int nt = (s >> 1) + 1;                // tiles covering keys <= q0+31
  int t0 = c ? 16 : 0;
  int t1 = c ? nt : (nt < 16 ? nt : 16);
  bool lastmask = (c == 1) || (s < 32); // diagonal tile is in this chunk

  for (int t = t0; t < t1; ++t) {
    int k0 = t * 64;
    bool mk = lastmask && (t == t1 - 1);
    short8 ka[4][2];
#pragma unroll
    for (int kg = 0; kg < 4; ++kg)
#pragma unroll
      for (int hh = 0; hh < 2; ++hh)
        ka[kg][hh] = *(const short8*)&Kb[(size_t)(k0 + kg * 16 + lr) * 64 + hh * 32 + 8 * lg];
    f32x4 sm[4][2];
    __builtin_amdgcn_s_setprio(1);
#pragma unroll
    for (int kg = 0; kg < 4; ++kg)
#pragma unroll
      for (int qc = 0; qc < 2; ++qc) {
        f32x4 z = {};
        z = mfma_bf16(ka[kg][0], qf[qc][0], z);
        z = mfma_bf16(ka[kg][1], qf[qc][1], z);
        sm[kg][qc] = z;
      }
    __builtin_amdgcn_s_setprio(0);
    short8 va[4][2];
#pragma unroll
    for (int dt = 0; dt < 4; ++dt)
#pragma unroll
      for (int hh = 0; hh < 2; ++hh)
        va[dt][hh] = *(const short8*)&Vb[(size_t)(dt * 16 + lr) * T_ + k0 + hh * 32 + 8 * lg];
    short8 pb[2][2];
#pragma unroll
    for (int qc = 0; qc < 2; ++qc) {
      int qa = q0 + qc * 16 + lr;
      float sv[16];
      float ps = 0.f;
#pragma unroll
      for (int kg = 0; kg < 4; ++kg)
#pragma unroll
        for (int rr = 0; rr < 4; ++rr) {
          float x = sm[kg][qc][rr];
          if (mk) {
            int key = k0 + kg * 16 + 4 * lg + rr;
            x = (key <= qa) ? x : -1e30f;
          }
          float p = __builtin_amdgcn_exp2f(x);   // exp2(-1e30) = 0 for masked
          sv[kg * 4 + rr] = p;
          ps += p;
        }
      lrow[qc] += ps;   // per-lane partial; cross-lane reduce deferred
#pragma unroll
      for (int c2 = 0; c2 < 2; ++c2) {
        u32x4 uu;
        uu[0] = cvt_pk_bf16(sv[c2 * 8 + 0], sv[c2 * 8 + 1]);
        uu[1] = cvt_pk_bf16(sv[c2 * 8 + 2], sv[c2 * 8 + 3]);
        uu[2] = cvt_pk_bf16(sv[c2 * 8 + 4], sv[c2 * 8 + 5]);
        uu[3] = cvt_pk_bf16(sv[c2 * 8 + 6], sv[c2 * 8 + 7]);
        pb[qc][c2] = __builtin_bit_cast(short8, uu);
      }
    }
    __builtin_amdgcn_s_setprio(1);
#pragma unroll
    for (int dt = 0; dt < 4; ++dt)
#pragma unroll
      for (int qc = 0; qc < 2; ++qc) {
        ao[dt][qc] = mfma_bf16(va[dt][0], pb[qc][0], ao[dt][qc]);
        ao[dt][qc] = mfma_bf16(va[dt][1], pb[qc][1], ao[dt][qc]);
      }
    __builtin_amdgcn_s_setprio(0);
  }

  // cross-lane reduce of row sums (lanes {l, l^16, l^32, l^48} share a q-column)
#pragma unroll
  for (int qc = 0; qc < 2; ++qc) {
    lrow[qc] += __shfl_xor(lrow[qc], 16);
    lrow[qc] += __shfl_xor(lrow[qc], 32);
  }

  if (s < 32) {
    // single chunk: normalize + per-wave transpose O^T(d,q)->O(q,d), store bf16
    u16* ow = sh + w * 2304;   // [32][72]
#pragma unroll
    for (int qc = 0; qc < 2; ++qc) {
      float inv = 1.0f / lrow[qc];
#pragma unroll
      for (int dt = 0; dt < 4; ++dt) {
        u32x2 pk;
        pk[0] = cvt_pk_bf16(ao[dt][qc][0] * inv, ao[dt][qc][1] * inv);
        pk[1] = cvt_pk_bf16(ao[dt][qc][2] * inv, ao[dt][qc][3] * inv);
        *(u32x2*)&ow[(qc * 16 + lr) * 72 + dt * 16 + 4 * lg] = pk;
      }
    }
    asm volatile("s_waitcnt lgkmcnt(0)" ::: "memory");  // wave-local write->read
    int r = l >> 1, hc = l & 1;
    const u16* srow = ow + r * 72 + hc * 32;
    u16* dst = O + ((size_t)(b * T_ + q0 + r)) * 768 + h * 64 + hc * 32;
#pragma unroll
    for (int j = 0; j < 4; ++j)
      *(uint4*)&dst[j * 8] = *(const uint4*)&srow[j * 8];
  } else {
    // partial: bf16 unnormalized O stored [q][d], f32 row sums
    int pidx = (head * 32 + (s - 32)) * 2 + c;
    u16* P = Pp + (size_t)pidx * 2048;
#pragma unroll
    for (int qc = 0; qc < 2; ++qc)
#pragma unroll
      for (int dt = 0; dt < 4; ++dt) {
        u32x2 pk;
        pk[0] = cvt_pk_bf16(ao[dt][qc][0], ao[dt][qc][1]);
        pk[1] = cvt_pk_bf16(ao[dt][qc][2], ao[dt][qc][3]);
        *(u32x2*)&P[(qc * 16 + lr) * 64 + dt * 16 + 4 * lg] = pk;
      }
    if (lg == 0) {
      Lp[pidx * 32 + lr] = lrow[0];
      Lp[pidx * 32 + 16 + lr] = lrow[1];
    }
  }
}

// combine two chunk partials for strips s>=32 (4 units per 256-thread block)
__global__ __launch_bounds__(256) void combine_kernel(const u16* __restrict__ Pp,
                                                      const float* __restrict__ Lp,
                                                      u16* __restrict__ O) {
  int d = threadIdx.x & 63;
  int u = blockIdx.x * 4 + (threadIdx.x >> 6);   // 0..767 = 24 heads x 32 strips
  int head = u % 24;
  int s = 32 + u / 24;
  int b = head / 12, h = head % 12;
  int p0 = (head * 32 + (s - 32)) * 2;
  const u16* P0 = Pp + (size_t)p0 * 2048;
  const u16* P1 = P0 + 2048;
  const float* L0 = Lp + p0 * 32;
  const float* L1 = L0 + 32;
#pragma unroll 4
  for (int q = 0; q < 32; ++q) {
    float o = bf2f(P0[q * 64 + d]) + bf2f(P1[q * 64 + d]);
    float ls = L0[q] + L1[q];
    O[((size_t)(b * T_ + s * 32 + q)) * 768 + h * 64 + d] = f2bf(o / ls);
  }
}

// ---------------- launch ----------------

extern "C" void kernel_launch(void* const* d_in, const int* in_sizes, int n_in,
                              void* d_out, int out_size, void* d_ws, size_t ws_size,
                              hipStream_t stream) {
  const float* x     = (const float*)d_in[0];
  const float* Wqkv  = (const float*)d_in[1];
  const float* bqkv  = (const float*)d_in[2];
  const float* Wproj = (const float*)d_in[3];
  const float* bproj = (const float*)d_in[4];
  float* out = (float*)d_out;
  char* ws = (char*)d_ws;
  u16* xb     = (u16*)(ws);                // 4096*768*2      = 6291456
  u16* wqkvT  = (u16*)(ws + 6291456);      // 2304*768*2      = 3538944
  u16* wprojT = (u16*)(ws + 9830400);      // 768*768*2       = 1179648
  u16* qb     = (u16*)(ws + 11010048);     // 24*2048*64*2    = 6291456
  u16* kb     = (u16*)(ws + 17301504);     // 6291456
  u16* vpb    = (u16*)(ws + 23592960);     // 6291456
  u16* ob     = (u16*)(ws + 29884416);     // 6291456  (total 36175872)
  // overlays (dead after gemm_qkv): partial O in xb (1536*4096B = 6291456 exact),
  // partial row-sums in wqkvT (1536*32*4 = 196608 B)
  u16* Pp = xb;
  float* Lp = (float*)wqkvT;

  prep_kernel<<<5376, 256, 0, stream>>>(x, Wqkv, Wproj, xb, wqkvT, wprojT);
  gemm_kernel<0, 64><<<dim3(18, 64), 256, 0, stream>>>(xb, wqkvT, bqkv, qb, kb, vpb, nullptr);
  attn_split_kernel<<<576, 256, 0, stream>>>(qb, kb, vpb, ob, Pp, Lp);
  combine_kernel<<<192, 256, 0, stream>>>(Pp, Lp, ob);
  gemm_kernel<1, 64><<<dim3(6, 64), 256, 0, stream>>>(ob, wprojT, bproj, nullptr, nullptr, nullptr, out);
}

// Round 11
// 94.716 us; speedup vs baseline: 1.3432x; 1.3432x over previous
//
#include <hip/hip_runtime.h>
#include <stdint.h>

typedef short short8 __attribute__((ext_vector_type(8)));
typedef short short4v __attribute__((ext_vector_type(4)));
typedef float f32x4 __attribute__((ext_vector_type(4)));
typedef unsigned int u32x2 __attribute__((ext_vector_type(2)));
typedef unsigned int u32x4 __attribute__((ext_vector_type(4)));
typedef unsigned short u16;
typedef unsigned int u32;

#define T_ 2048
#define QK_SCALE 0.180336878f   // 0.125 * log2(e): softmax in log2 domain

__device__ inline u16 f2bf(float f) {
  unsigned u = __builtin_bit_cast(unsigned, f);
  u += 0x7fffu + ((u >> 16) & 1u);   // RNE; inputs finite
  return (u16)(u >> 16);
}

__device__ inline float bf2f(u16 v) {
  return __builtin_bit_cast(float, (u32)v << 16);
}

__device__ inline u32 cvt_pk_bf16(float lo, float hi) {
  u32 r;
  asm("v_cvt_pk_bf16_f32 %0, %1, %2" : "=v"(r) : "v"(lo), "v"(hi));
  return r;
}

__device__ inline f32x4 mfma_bf16(short8 a, short8 b, f32x4 c) {
  return __builtin_amdgcn_mfma_f32_16x16x32_bf16(a, b, c, 0, 0, 0);
}

// async global->LDS, 16B per lane; lds base must be wave-uniform
__device__ inline void gload16(const u16* g, u16* l) {
  __builtin_amdgcn_global_load_lds(
      (const __attribute__((address_space(1))) void*)g,
      (__attribute__((address_space(3))) void*)l, 16, 0, 0);
}

// ---------------- fused prep: convert x + transpose-convert both weights ----------------

__device__ inline void tile_transpose(const float* __restrict__ W, u16* __restrict__ Wt,
                                      int R, int Ccols, int c0, int r0, int t,
                                      float (*tile)[33]) {
  int tr = t >> 3, tc = (t & 7) * 4;
  float4 v = *(const float4*)&W[(size_t)(r0 + tr) * Ccols + c0 + tc];
  tile[tr][tc + 0] = v.x; tile[tr][tc + 1] = v.y;
  tile[tr][tc + 2] = v.z; tile[tr][tc + 3] = v.w;
  __syncthreads();
  short4v o;
#pragma unroll
  for (int i = 0; i < 4; ++i) o[i] = (short)f2bf(tile[tc + i][tr]);
  *(short4v*)&Wt[(size_t)(c0 + tr) * R + r0 + tc] = o;
}

__global__ __launch_bounds__(256) void prep_kernel(const float* __restrict__ x,
                                                   const float* __restrict__ Wqkv,
                                                   const float* __restrict__ Wproj,
                                                   u16* __restrict__ xb,
                                                   u16* __restrict__ wqkvT,
                                                   u16* __restrict__ wprojT) {
  __shared__ float tile[32][33];
  int bid = blockIdx.x, t = threadIdx.x;
  if (bid < 3072) {
    int i = (bid * 256 + t) * 4;
    float4 v = *(const float4*)&x[i];
    short4v o;
    o[0] = (short)f2bf(v.x); o[1] = (short)f2bf(v.y);
    o[2] = (short)f2bf(v.z); o[3] = (short)f2bf(v.w);
    *(short4v*)&xb[i] = o;
  } else if (bid < 3072 + 1728) {
    int t2 = bid - 3072;
    tile_transpose(Wqkv, wqkvT, 768, 2304, (t2 % 72) * 32, (t2 / 72) * 32, t, tile);
  } else {
    int t3 = bid - 4800;
    tile_transpose(Wproj, wprojT, 768, 768, (t3 % 24) * 32, (t3 / 24) * 32, t, tile);
  }
}

// ---------------- MTILE x 128 GEMM (gload_lds w16 + XOR swizzle + XCD chunking) ----------------

template <int MODE, int MTILE>
__global__ __launch_bounds__(256) void gemm_kernel(const u16* __restrict__ A,
                                                   const u16* __restrict__ Bt,
                                                   const float* __restrict__ bias,
                                                   u16* __restrict__ qb,
                                                   u16* __restrict__ kb,
                                                   u16* __restrict__ vpb,
                                                   float* __restrict__ out) {
  constexpr int MF = MTILE / 32;            // m-fragments per wave
  __shared__ u16 S[MTILE * 64 + 8192];      // As | Bs (reused as transpose buf)
  u16* As = S;
  u16* Bs = S + MTILE * 64;
  int tid = threadIdx.x, w = tid >> 6, l = tid & 63, lg = l >> 4, lr = l & 15;
  int nwg = gridDim.x * gridDim.y;
  int hw = blockIdx.y * gridDim.x + blockIdx.x;
  int logical = (hw & 7) * (nwg >> 3) + (hw >> 3);
  int n0 = (logical % gridDim.x) * 128, m0 = (logical / gridDim.x) * MTILE;
  int wm = (w >> 1) * (MTILE / 2), wn = (w & 1) * 64;
  f32x4 acc[MF][4] = {};
  int rsub = l >> 3;
  int sc = ((l & 7) ^ rsub) * 8;
  for (int kt = 0; kt < 12; ++kt) {
    int k0 = kt * 64;
    __syncthreads();
#pragma unroll
    for (int j = 0; j < MF; ++j) {
      int row = w * (MTILE / 4) + j * 8 + rsub;
      gload16(&A[(size_t)(m0 + row) * 768 + k0 + sc], &As[(w * MF + j) * 512]);
    }
#pragma unroll
    for (int j = 0; j < 4; ++j) {
      int row = w * 32 + j * 8 + rsub;
      gload16(&Bt[(size_t)(n0 + row) * 768 + k0 + sc], &Bs[(w * 4 + j) * 512]);
    }
    __syncthreads();
    short8 a[MF][2], b[4][2];
#pragma unroll
    for (int h = 0; h < 2; ++h) {
#pragma unroll
      for (int mf = 0; mf < MF; ++mf) {
        int cw = ((h * 4 + lg) ^ (lr & 7)) * 8;
        a[mf][h] = *(const short8*)&As[(wm + mf * 16 + lr) * 64 + cw];
      }
#pragma unroll
      for (int nf = 0; nf < 4; ++nf) {
        int cw = ((h * 4 + lg) ^ (lr & 7)) * 8;
        b[nf][h] = *(const short8*)&Bs[(wn + nf * 16 + lr) * 64 + cw];
      }
    }
#pragma unroll
    for (int h = 0; h < 2; ++h)
#pragma unroll
      for (int mf = 0; mf < MF; ++mf)
#pragma unroll
        for (int nf = 0; nf < 4; ++nf)
          acc[mf][nf] = mfma_bf16(a[mf][h], b[nf][h], acc[mf][nf]);
  }

  if constexpr (MODE == 0) {
    int sec = (n0 >= 1536) ? 2 : (n0 >= 768 ? 1 : 0);
    int ncol0 = n0 - sec * 768;
    if (sec < 2) {
#pragma unroll
      for (int nf = 0; nf < 4; ++nf) {
        int nn = wn + nf * 16 + lr;
        float bv = bias[n0 + nn];
        int c = ncol0 + nn;
        int hh = c >> 6, d = c & 63;
#pragma unroll
        for (int mf = 0; mf < MF; ++mf)
#pragma unroll
          for (int rr = 0; rr < 4; ++rr) {
            int m = m0 + wm + mf * 16 + 4 * lg + rr;
            int bb = m >> 11, tt = m & 2047;
            int bh = bb * 12 + hh;
            float v = acc[mf][nf][rr] + bv;
            if (sec == 0) qb[((size_t)bh * T_ + tt) * 64 + d] = f2bf(v * QK_SCALE);
            else          kb[((size_t)bh * T_ + tt) * 64 + d] = f2bf(v);
          }
      }
    } else {
      // V^T: transpose in LDS (p5 key-permutation folded into column), coalesced rows out.
      __syncthreads();
#pragma unroll
      for (int nf = 0; nf < 4; ++nf) {
        int row = wn + nf * 16 + lr;
        float bv = bias[n0 + row];
        int swz = (row & 7) << 3;
#pragma unroll
        for (int mf = 0; mf < MF; ++mf) {
          int pcol0 = wm + (mf >> 1) * 32 + 8 * lg + 4 * (mf & 1);
          u32x2 pk;
          pk[0] = cvt_pk_bf16(acc[mf][nf][0] + bv, acc[mf][nf][1] + bv);
          pk[1] = cvt_pk_bf16(acc[mf][nf][2] + bv, acc[mf][nf][3] + bv);
          *(u32x2*)&S[row * MTILE + (pcol0 ^ swz)] = pk;
        }
      }
      __syncthreads();
      constexpr int CPT = MTILE / 2;
      int rowo = tid >> 1, half = tid & 1;
      int c = ncol0 + rowo;
      int d = c & 63, hh = c >> 6;
      int bh = (m0 >> 11) * 12 + hh;
      u16* dst = vpb + ((size_t)bh * 64 + d) * T_ + (m0 & 2047) + half * CPT;
      int swzo = (rowo & 7) << 3;
#pragma unroll
      for (int i = 0; i < CPT / 8; ++i) {
        int col = half * CPT + i * 8;
        uint4 v = *(const uint4*)&S[rowo * MTILE + (col ^ swzo)];
        *(uint4*)&dst[i * 8] = v;
      }
    }
  } else {
#pragma unroll
    for (int nf = 0; nf < 4; ++nf) {
      int n = n0 + wn + nf * 16 + lr;
      float bv = bias[n];
#pragma unroll
      for (int mf = 0; mf < MF; ++mf)
#pragma unroll
        for (int rr = 0; rr < 4; ++rr) {
          int m = m0 + wm + mf * 16 + 4 * lg + rr;
          out[(size_t)m * 768 + n] = acc[mf][nf][rr] + bv;
        }
    }
  }
}

// ---------------- flash attention: R8 engine + split-K work units ----------------
// Unit = (head, 64-q strip s in 0..31, chunk c). Strips s>=16 split into two
// <=16-tile chunks (c=0: tiles [0,h1), c=1: [h1, s+1)); s<16 single-chunk.
// Inner loop identical to R8 (LDS dbuf staging, syncthreads, setprio).
// Partials (bf16 O + f32 rowsum) combine by ADDITION (no-max softmax).

__global__ __launch_bounds__(256) void attn_kernel(const u16* __restrict__ Q,
                                                   const u16* __restrict__ K,
                                                   const u16* __restrict__ Vp,
                                                   u16* __restrict__ O,
                                                   u16* __restrict__ Pp,
                                                   float* __restrict__ Lp) {
  __shared__ u16 sh[16384];  // K dbuf 2x4096, V dbuf 2x4096 (swizzled linear)
  int tid = threadIdx.x;
  int w = tid >> 6, l = tid & 63, lg = l >> 4, lr = l & 15;
  int u = blockIdx.x;
  int head = u % 24;                  // 24 % 8 == 0: head striping across XCDs
  int v = u / 24;                     // 0..47, work-descending-ish
  int s, c;
  if (v < 32) { s = 31 - (v >> 1); c = v & 1; }   // split strips 31..16
  else        { s = 47 - v; c = 0; }              // single strips 15..0
  bool ispartial = (v < 32);
  int b = head / 12, h = head % 12;
  int q0 = s * 64;
  int q0w = q0 + w * 16;              // this wave's 16 q-rows
  const u16* Qb = Q + (size_t)head * T_ * 64;
  const u16* Kb = K + (size_t)head * T_ * 64;
  const u16* Vb = Vp + (size_t)head * 64 * T_;

  short8 qf0 = *(const short8*)&Qb[(size_t)(q0w + lr) * 64 + 8 * lg];
  short8 qf1 = *(const short8*)&Qb[(size_t)(q0w + lr) * 64 + 32 + 8 * lg];

  f32x4 ao[4] = {};
  float lrow = 0.f;
  int rsub = l >> 3;
  int scs = ((l & 7) ^ rsub) * 8;
  int nt = s + 1;
  int h1 = (s + 2) >> 1;              // ceil((s+1)/2)
  int t0 = (ispartial && c) ? h1 : 0;
  int tEnd = (ispartial && !c) ? h1 : nt;

  // prologue: stage tile t0 (4 waves x 2 issues cover 64 rows of K and V)
#pragma unroll
  for (int j = 0; j < 2; ++j) {
    int ci = w * 2 + j;
    int row = ci * 8 + rsub;
    gload16(&Kb[(size_t)(t0 * 64 + row) * 64 + scs], &sh[ci * 512]);
    gload16(&Vb[(size_t)row * T_ + t0 * 64 + scs], &sh[8192 + ci * 512]);
  }
  __syncthreads();

  for (int t = t0; t < tEnd; ++t) {
    int cur = (t - t0) & 1;
    int k0 = t * 64;
    if (t + 1 < tEnd) {
      int k1 = k0 + 64;
#pragma unroll
      for (int j = 0; j < 2; ++j) {
        int ci = w * 2 + j;
        int row = ci * 8 + rsub;
        gload16(&Kb[(size_t)(k1 + row) * 64 + scs], &sh[(cur ^ 1) * 4096 + ci * 512]);
        gload16(&Vb[(size_t)row * T_ + k1 + scs], &sh[8192 + (cur ^ 1) * 4096 + ci * 512]);
      }
    }
    if (k0 <= q0w + 15) {   // wave-uniform: skip tiles fully above this wave's diagonal
      const u16* ks = sh + cur * 4096;
      const u16* vs = sh + 8192 + cur * 4096;
      f32x4 sm[4];
      __builtin_amdgcn_s_setprio(1);
#pragma unroll
      for (int kg = 0; kg < 4; ++kg) {
        short8 ka0 = *(const short8*)&ks[(kg * 16 + lr) * 64 + ((lg ^ (lr & 7)) * 8)];
        short8 ka1 = *(const short8*)&ks[(kg * 16 + lr) * 64 + (((4 + lg) ^ (lr & 7)) * 8)];
        f32x4 z = {};
        z = mfma_bf16(ka0, qf0, z);
        z = mfma_bf16(ka1, qf1, z);
        sm[kg] = z;
      }
      __builtin_amdgcn_s_setprio(0);
      int qa = q0w + lr;
      bool domask = (k0 + 63 > q0w);
      float sv[16];
      float ps = 0.f;
#pragma unroll
      for (int kg = 0; kg < 4; ++kg)
#pragma unroll
        for (int rr = 0; rr < 4; ++rr) {
          float x = sm[kg][rr];
          if (domask) {
            int key = k0 + kg * 16 + 4 * lg + rr;
            x = (key <= qa) ? x : -1e30f;
          }
          float p = __builtin_amdgcn_exp2f(x);   // exp2(-1e30) = 0 for masked
          sv[kg * 4 + rr] = p;
          ps += p;
        }
      ps += __shfl_xor(ps, 16);
      ps += __shfl_xor(ps, 32);
      lrow += ps;
      short8 pb[2];
#pragma unroll
      for (int c2 = 0; c2 < 2; ++c2) {
        u32x4 uu;
        uu[0] = cvt_pk_bf16(sv[c2 * 8 + 0], sv[c2 * 8 + 1]);
        uu[1] = cvt_pk_bf16(sv[c2 * 8 + 2], sv[c2 * 8 + 3]);
        uu[2] = cvt_pk_bf16(sv[c2 * 8 + 4], sv[c2 * 8 + 5]);
        uu[3] = cvt_pk_bf16(sv[c2 * 8 + 6], sv[c2 * 8 + 7]);
        pb[c2] = __builtin_bit_cast(short8, uu);
      }
      __builtin_amdgcn_s_setprio(1);
#pragma unroll
      for (int dt = 0; dt < 4; ++dt) {
        short8 va0 = *(const short8*)&vs[(dt * 16 + lr) * 64 + ((lg ^ (lr & 7)) * 8)];
        short8 va1 = *(const short8*)&vs[(dt * 16 + lr) * 64 + (((4 + lg) ^ (lr & 7)) * 8)];
        ao[dt] = mfma_bf16(va0, pb[0], ao[dt]);
        ao[dt] = mfma_bf16(va1, pb[1], ao[dt]);
      }
      __builtin_amdgcn_s_setprio(0);
    }
    __syncthreads();
  }

  // epilogue: O^T(d,q) -> (q,d) via per-wave padded LDS (reuse sh)
  u16* ow = sh + w * 1152;   // [16][72]
  float inv = ispartial ? 1.0f : (1.0f / lrow);
#pragma unroll
  for (int dt = 0; dt < 4; ++dt) {
    u32x2 pk;
    pk[0] = cvt_pk_bf16(ao[dt][0] * inv, ao[dt][1] * inv);
    pk[1] = cvt_pk_bf16(ao[dt][2] * inv, ao[dt][3] * inv);
    *(u32x2*)&ow[lr * 72 + dt * 16 + 4 * lg] = pk;
  }
  __syncthreads();
  int r = l >> 2, hc = l & 3;
  const u16* srow = sh + w * 1152 + r * 72 + hc * 16;
  if (!ispartial) {
    u16* dst = O + ((size_t)(b * T_ + q0w + r)) * 768 + h * 64 + hc * 16;
    *(uint4*)&dst[0] = *(const uint4*)&srow[0];
    *(uint4*)&dst[8] = *(const uint4*)&srow[8];
  } else {
    int pidx = (head * 16 + (s - 16)) * 2 + c;
    u16* dst = Pp + (size_t)pidx * 4096 + (w * 16 + r) * 64 + hc * 16;
    *(uint4*)&dst[0] = *(const uint4*)&srow[0];
    *(uint4*)&dst[8] = *(const uint4*)&srow[8];
    if (lg == 0) Lp[pidx * 64 + w * 16 + lr] = lrow;
  }
}

// combine two chunk partials for strips s>=16 (4 units per 256-thread block)
__global__ __launch_bounds__(256) void combine_kernel(const u16* __restrict__ Pp,
                                                      const float* __restrict__ Lp,
                                                      u16* __restrict__ O) {
  int d = threadIdx.x & 63;
  int u = blockIdx.x * 4 + (threadIdx.x >> 6);   // 0..383 = 24 heads x 16 strips
  int head = u % 24;
  int s = 16 + u / 24;
  int b = head / 12, h = head % 12;
  int p0 = (head * 16 + (s - 16)) * 2;
  const u16* P0 = Pp + (size_t)p0 * 4096;
  const u16* P1 = P0 + 4096;
  const float* L0 = Lp + p0 * 64;
  const float* L1 = L0 + 64;
#pragma unroll 4
  for (int q = 0; q < 64; ++q) {
    float o = bf2f(P0[q * 64 + d]) + bf2f(P1[q * 64 + d]);
    float ls = L0[q] + L1[q];
    O[((size_t)(b * T_ + s * 64 + q)) * 768 + h * 64 + d] = f2bf(o / ls);
  }
}

// ---------------- launch ----------------

extern "C" void kernel_launch(void* const* d_in, const int* in_sizes, int n_in,
                              void* d_out, int out_size, void* d_ws, size_t ws_size,
                              hipStream_t stream) {
  const float* x     = (const float*)d_in[0];
  const float* Wqkv  = (const float*)d_in[1];
  const float* bqkv  = (const float*)d_in[2];
  const float* Wproj = (const float*)d_in[3];
  const float* bproj = (const float*)d_in[4];
  float* out = (float*)d_out;
  char* ws = (char*)d_ws;
  u16* xb     = (u16*)(ws);                // 4096*768*2      = 6291456
  u16* wqkvT  = (u16*)(ws + 6291456);      // 2304*768*2      = 3538944
  u16* wprojT = (u16*)(ws + 9830400);      // 768*768*2       = 1179648
  u16* qb     = (u16*)(ws + 11010048);     // 24*2048*64*2    = 6291456
  u16* kb     = (u16*)(ws + 17301504);     // 6291456
  u16* vpb    = (u16*)(ws + 23592960);     // 6291456
  u16* ob     = (u16*)(ws + 29884416);     // 6291456  (total 36175872)
  // overlays (dead after gemm_qkv): partials in xb (768*8192B = 6291456 exact),
  // row-sums in wqkvT (768*64*4 = 196608 B)
  u16* Pp = xb;
  float* Lp = (float*)wqkvT;

  prep_kernel<<<5376, 256, 0, stream>>>(x, Wqkv, Wproj, xb, wqkvT, wprojT);
  gemm_kernel<0, 64><<<dim3(18, 64), 256, 0, stream>>>(xb, wqkvT, bqkv, qb, kb, vpb, nullptr);
  attn_kernel<<<1152, 256, 0, stream>>>(qb, kb, vpb, ob, Pp, Lp);
  combine_kernel<<<96, 256, 0, stream>>>(Pp, Lp, ob);
  gemm_kernel<1, 64><<<dim3(6, 64), 256, 0, stream>>>(ob, wprojT, bproj, nullptr, nullptr, nullptr, out);
}

// Round 12
// 78.449 us; speedup vs baseline: 1.6217x; 1.2074x over previous
//
#include <hip/hip_runtime.h>
#include <stdint.h>

typedef short short8 __attribute__((ext_vector_type(8)));
typedef short short4v __attribute__((ext_vector_type(4)));
typedef float f32x4 __attribute__((ext_vector_type(4)));
typedef unsigned int u32x2 __attribute__((ext_vector_type(2)));
typedef unsigned int u32x4 __attribute__((ext_vector_type(4)));
typedef unsigned short u16;
typedef unsigned int u32;

#define T_ 2048
#define QK_SCALE 0.180336878f   // 0.125 * log2(e): softmax in log2 domain

__device__ inline u16 f2bf(float f) {
  unsigned u = __builtin_bit_cast(unsigned, f);
  u += 0x7fffu + ((u >> 16) & 1u);   // RNE; inputs finite
  return (u16)(u >> 16);
}

__device__ inline u32 cvt_pk_bf16(float lo, float hi) {
  u32 r;
  asm("v_cvt_pk_bf16_f32 %0, %1, %2" : "=v"(r) : "v"(lo), "v"(hi));
  return r;
}

__device__ inline f32x4 mfma_bf16(short8 a, short8 b, f32x4 c) {
  return __builtin_amdgcn_mfma_f32_16x16x32_bf16(a, b, c, 0, 0, 0);
}

// async global->LDS, 16B per lane; lds base must be wave-uniform
__device__ inline void gload16(const u16* g, u16* l) {
  __builtin_amdgcn_global_load_lds(
      (const __attribute__((address_space(1))) void*)g,
      (__attribute__((address_space(3))) void*)l, 16, 0, 0);
}

// ---------------- fused prep: convert x + transpose-convert both weights ----------------

__device__ inline void tile_transpose(const float* __restrict__ W, u16* __restrict__ Wt,
                                      int R, int Ccols, int c0, int r0, int t,
                                      float (*tile)[33]) {
  int tr = t >> 3, tc = (t & 7) * 4;
  float4 v = *(const float4*)&W[(size_t)(r0 + tr) * Ccols + c0 + tc];
  tile[tr][tc + 0] = v.x; tile[tr][tc + 1] = v.y;
  tile[tr][tc + 2] = v.z; tile[tr][tc + 3] = v.w;
  __syncthreads();
  short4v o;
#pragma unroll
  for (int i = 0; i < 4; ++i) o[i] = (short)f2bf(tile[tc + i][tr]);
  *(short4v*)&Wt[(size_t)(c0 + tr) * R + r0 + tc] = o;
}

__global__ __launch_bounds__(256) void prep_kernel(const float* __restrict__ x,
                                                   const float* __restrict__ Wqkv,
                                                   const float* __restrict__ Wproj,
                                                   u16* __restrict__ xb,
                                                   u16* __restrict__ wqkvT,
                                                   u16* __restrict__ wprojT) {
  __shared__ float tile[32][33];
  int bid = blockIdx.x, t = threadIdx.x;
  if (bid < 3072) {
    int i = (bid * 256 + t) * 4;
    float4 v = *(const float4*)&x[i];
    short4v o;
    o[0] = (short)f2bf(v.x); o[1] = (short)f2bf(v.y);
    o[2] = (short)f2bf(v.z); o[3] = (short)f2bf(v.w);
    *(short4v*)&xb[i] = o;
  } else if (bid < 3072 + 1728) {
    int t2 = bid - 3072;
    tile_transpose(Wqkv, wqkvT, 768, 2304, (t2 % 72) * 32, (t2 / 72) * 32, t, tile);
  } else {
    int t3 = bid - 4800;
    tile_transpose(Wproj, wprojT, 768, 768, (t3 % 24) * 32, (t3 / 24) * 32, t, tile);
  }
}

// ---------------- MTILE x 128 GEMM (gload_lds w16 + XOR swizzle + XCD chunking) ----------------

template <int MODE, int MTILE>
__global__ __launch_bounds__(256) void gemm_kernel(const u16* __restrict__ A,
                                                   const u16* __restrict__ Bt,
                                                   const float* __restrict__ bias,
                                                   u16* __restrict__ qb,
                                                   u16* __restrict__ kb,
                                                   u16* __restrict__ vpb,
                                                   float* __restrict__ out) {
  constexpr int MF = MTILE / 32;            // m-fragments per wave
  __shared__ u16 S[MTILE * 64 + 8192];      // As | Bs (reused as transpose buf)
  u16* As = S;
  u16* Bs = S + MTILE * 64;
  int tid = threadIdx.x, w = tid >> 6, l = tid & 63, lg = l >> 4, lr = l & 15;
  int nwg = gridDim.x * gridDim.y;
  int hw = blockIdx.y * gridDim.x + blockIdx.x;
  int logical = (hw & 7) * (nwg >> 3) + (hw >> 3);
  int n0 = (logical % gridDim.x) * 128, m0 = (logical / gridDim.x) * MTILE;
  int wm = (w >> 1) * (MTILE / 2), wn = (w & 1) * 64;
  f32x4 acc[MF][4] = {};
  int rsub = l >> 3;
  int sc = ((l & 7) ^ rsub) * 8;
  for (int kt = 0; kt < 12; ++kt) {
    int k0 = kt * 64;
    __syncthreads();
#pragma unroll
    for (int j = 0; j < MF; ++j) {
      int row = w * (MTILE / 4) + j * 8 + rsub;
      gload16(&A[(size_t)(m0 + row) * 768 + k0 + sc], &As[(w * MF + j) * 512]);
    }
#pragma unroll
    for (int j = 0; j < 4; ++j) {
      int row = w * 32 + j * 8 + rsub;
      gload16(&Bt[(size_t)(n0 + row) * 768 + k0 + sc], &Bs[(w * 4 + j) * 512]);
    }
    __syncthreads();
    short8 a[MF][2], b[4][2];
#pragma unroll
    for (int h = 0; h < 2; ++h) {
#pragma unroll
      for (int mf = 0; mf < MF; ++mf) {
        int cw = ((h * 4 + lg) ^ (lr & 7)) * 8;
        a[mf][h] = *(const short8*)&As[(wm + mf * 16 + lr) * 64 + cw];
      }
#pragma unroll
      for (int nf = 0; nf < 4; ++nf) {
        int cw = ((h * 4 + lg) ^ (lr & 7)) * 8;
        b[nf][h] = *(const short8*)&Bs[(wn + nf * 16 + lr) * 64 + cw];
      }
    }
#pragma unroll
    for (int h = 0; h < 2; ++h)
#pragma unroll
      for (int mf = 0; mf < MF; ++mf)
#pragma unroll
        for (int nf = 0; nf < 4; ++nf)
          acc[mf][nf] = mfma_bf16(a[mf][h], b[nf][h], acc[mf][nf]);
  }

  if constexpr (MODE == 0) {
    int sec = (n0 >= 1536) ? 2 : (n0 >= 768 ? 1 : 0);
    int ncol0 = n0 - sec * 768;
    if (sec < 2) {
#pragma unroll
      for (int nf = 0; nf < 4; ++nf) {
        int nn = wn + nf * 16 + lr;
        float bv = bias[n0 + nn];
        int c = ncol0 + nn;
        int hh = c >> 6, d = c & 63;
#pragma unroll
        for (int mf = 0; mf < MF; ++mf)
#pragma unroll
          for (int rr = 0; rr < 4; ++rr) {
            int m = m0 + wm + mf * 16 + 4 * lg + rr;
            int bb = m >> 11, tt = m & 2047;
            int bh = bb * 12 + hh;
            float v = acc[mf][nf][rr] + bv;
            if (sec == 0) qb[((size_t)bh * T_ + tt) * 64 + d] = f2bf(v * QK_SCALE);
            else          kb[((size_t)bh * T_ + tt) * 64 + d] = f2bf(v);
          }
      }
    } else {
      // V^T: transpose in LDS (p5 key-permutation folded into column), coalesced rows out.
      __syncthreads();
#pragma unroll
      for (int nf = 0; nf < 4; ++nf) {
        int row = wn + nf * 16 + lr;
        float bv = bias[n0 + row];
        int swz = (row & 7) << 3;
#pragma unroll
        for (int mf = 0; mf < MF; ++mf) {
          int pcol0 = wm + (mf >> 1) * 32 + 8 * lg + 4 * (mf & 1);
          u32x2 pk;
          pk[0] = cvt_pk_bf16(acc[mf][nf][0] + bv, acc[mf][nf][1] + bv);
          pk[1] = cvt_pk_bf16(acc[mf][nf][2] + bv, acc[mf][nf][3] + bv);
          *(u32x2*)&S[row * MTILE + (pcol0 ^ swz)] = pk;
        }
      }
      __syncthreads();
      constexpr int CPT = MTILE / 2;
      int rowo = tid >> 1, half = tid & 1;
      int c = ncol0 + rowo;
      int d = c & 63, hh = c >> 6;
      int bh = (m0 >> 11) * 12 + hh;
      u16* dst = vpb + ((size_t)bh * 64 + d) * T_ + (m0 & 2047) + half * CPT;
      int swzo = (rowo & 7) << 3;
#pragma unroll
      for (int i = 0; i < CPT / 8; ++i) {
        int col = half * CPT + i * 8;
        uint4 v = *(const uint4*)&S[rowo * MTILE + (col ^ swzo)];
        *(uint4*)&dst[i * 8] = v;
      }
    }
  } else {
#pragma unroll
    for (int nf = 0; nf < 4; ++nf) {
      int n = n0 + wn + nf * 16 + lr;
      float bv = bias[n];
#pragma unroll
      for (int mf = 0; mf < MF; ++mf)
#pragma unroll
        for (int rr = 0; rr < 4; ++rr) {
          int m = m0 + wm + mf * 16 + 4 * lg + rr;
          out[(size_t)m * 768 + n] = acc[mf][nf][rr] + bv;
        }
    }
  }
}

// ---------------- flash attention (R8 structure + micro-opts) ----------------
// Q,K: [BH][T][64] bf16 (Q pre-scaled by 0.125*log2e), Vp: [BH][64][T] bf16
// (key-permuted), O: [B*T][768] bf16. 4 waves x 16 q, 64-q blocks, 768 blocks.
// Micro-opts vs R8: (1) mask code only on last tile (provably the only tile
// needing it); (2) lrow cross-lane reduce deferred to epilogue; (3) V ds_reads
// issued before QK MFMA so they overlap the softmax VALU phase.

__global__ __launch_bounds__(256) void attn_kernel(const u16* __restrict__ Q,
                                                   const u16* __restrict__ K,
                                                   const u16* __restrict__ Vp,
                                                   u16* __restrict__ O) {
  __shared__ u16 sh[16384];  // K dbuf 2x4096, V dbuf 2x4096 (swizzled linear)
  int tid = threadIdx.x;
  int w = tid >> 6, l = tid & 63, lg = l >> 4, lr = l & 15;
  int idx = blockIdx.x;
  int head = idx % 24;                 // 24 % 8 == 0: same head -> same XCD (L2 reuse)
  int qblk = 31 - idx / 24;            // big-work blocks dispatch first
  int b = head / 12, h = head % 12;
  int q0 = qblk * 64;
  int q0w = q0 + w * 16;               // this wave's 16 q-rows
  const u16* Qb = Q + (size_t)head * T_ * 64;
  const u16* Kb = K + (size_t)head * T_ * 64;
  const u16* Vb = Vp + (size_t)head * 64 * T_;

  short8 qf0 = *(const short8*)&Qb[(size_t)(q0w + lr) * 64 + 8 * lg];
  short8 qf1 = *(const short8*)&Qb[(size_t)(q0w + lr) * 64 + 32 + 8 * lg];

  f32x4 ao[4] = {};
  float lrow = 0.f;                    // per-lane partial row-sum (reduced in epilogue)
  int rsub = l >> 3;
  int scs = ((l & 7) ^ rsub) * 8;
  const int nt = qblk + 1;             // 64-key tiles covering keys <= q0+63

  // prologue: stage tile 0 (4 waves x 2 issues cover 64 rows of K and V)
#pragma unroll
  for (int j = 0; j < 2; ++j) {
    int ci = w * 2 + j;
    int row = ci * 8 + rsub;
    gload16(&Kb[(size_t)row * 64 + scs], &sh[ci * 512]);
    gload16(&Vb[(size_t)row * T_ + scs], &sh[8192 + ci * 512]);
  }
  __syncthreads();

  for (int t = 0; t < nt; ++t) {
    int cur = t & 1;
    int k0 = t * 64;
    if (t + 1 < nt) {
      int k1 = k0 + 64;
#pragma unroll
      for (int j = 0; j < 2; ++j) {
        int ci = w * 2 + j;
        int row = ci * 8 + rsub;
        gload16(&Kb[(size_t)(k1 + row) * 64 + scs], &sh[(cur ^ 1) * 4096 + ci * 512]);
        gload16(&Vb[(size_t)row * T_ + k1 + scs], &sh[8192 + (cur ^ 1) * 4096 + ci * 512]);
      }
    }
    if (k0 <= q0w + 15) {   // wave-uniform: skip tiles fully above this wave's diagonal
      const u16* ks = sh + cur * 4096;
      const u16* vs = sh + 8192 + cur * 4096;
      // issue all LDS reads up front: V loads overlap the softmax VALU phase
      short8 ka0[4], ka1[4], va0[4], va1[4];
#pragma unroll
      for (int kg = 0; kg < 4; ++kg) {
        ka0[kg] = *(const short8*)&ks[(kg * 16 + lr) * 64 + ((lg ^ (lr & 7)) * 8)];
        ka1[kg] = *(const short8*)&ks[(kg * 16 + lr) * 64 + (((4 + lg) ^ (lr & 7)) * 8)];
      }
#pragma unroll
      for (int dt = 0; dt < 4; ++dt) {
        va0[dt] = *(const short8*)&vs[(dt * 16 + lr) * 64 + ((lg ^ (lr & 7)) * 8)];
        va1[dt] = *(const short8*)&vs[(dt * 16 + lr) * 64 + (((4 + lg) ^ (lr & 7)) * 8)];
      }
      f32x4 sm[4];
      __builtin_amdgcn_s_setprio(1);
#pragma unroll
      for (int kg = 0; kg < 4; ++kg) {
        f32x4 z = {};
        z = mfma_bf16(ka0[kg], qf0, z);
        z = mfma_bf16(ka1[kg], qf1, z);
        sm[kg] = z;
      }
      __builtin_amdgcn_s_setprio(0);
      float sv[16];
      float ps = 0.f;
      if (t == nt - 1) {               // only the last tile crosses the diagonal
        int qa = q0w + lr;
#pragma unroll
        for (int kg = 0; kg < 4; ++kg)
#pragma unroll
          for (int rr = 0; rr < 4; ++rr) {
            int key = k0 + kg * 16 + 4 * lg + rr;
            float x = (key <= qa) ? sm[kg][rr] : -1e30f;
            float p = __builtin_amdgcn_exp2f(x);   // exp2(-1e30) = 0
            sv[kg * 4 + rr] = p;
            ps += p;
          }
      } else {                         // mask-free fast path
#pragma unroll
        for (int kg = 0; kg < 4; ++kg)
#pragma unroll
          for (int rr = 0; rr < 4; ++rr) {
            float p = __builtin_amdgcn_exp2f(sm[kg][rr]);
            sv[kg * 4 + rr] = p;
            ps += p;
          }
      }
      lrow += ps;
      short8 pb[2];
#pragma unroll
      for (int c2 = 0; c2 < 2; ++c2) {
        u32x4 uu;
        uu[0] = cvt_pk_bf16(sv[c2 * 8 + 0], sv[c2 * 8 + 1]);
        uu[1] = cvt_pk_bf16(sv[c2 * 8 + 2], sv[c2 * 8 + 3]);
        uu[2] = cvt_pk_bf16(sv[c2 * 8 + 4], sv[c2 * 8 + 5]);
        uu[3] = cvt_pk_bf16(sv[c2 * 8 + 6], sv[c2 * 8 + 7]);
        pb[c2] = __builtin_bit_cast(short8, uu);
      }
      __builtin_amdgcn_s_setprio(1);
#pragma unroll
      for (int dt = 0; dt < 4; ++dt) {
        ao[dt] = mfma_bf16(va0[dt], pb[0], ao[dt]);
        ao[dt] = mfma_bf16(va1[dt], pb[1], ao[dt]);
      }
      __builtin_amdgcn_s_setprio(0);
    }
    __syncthreads();
  }

  // epilogue: reduce row-sums (lanes {l, l^16, l^32, l^48} share q = lr),
  // then O^T(d,q) -> O(q,d) via per-wave padded LDS (reuse sh)
  lrow += __shfl_xor(lrow, 16);
  lrow += __shfl_xor(lrow, 32);
  u16* ow = sh + w * 1152;   // [16][72]
  float inv = 1.0f / lrow;
#pragma unroll
  for (int dt = 0; dt < 4; ++dt) {
    u32x2 pk;
    pk[0] = cvt_pk_bf16(ao[dt][0] * inv, ao[dt][1] * inv);
    pk[1] = cvt_pk_bf16(ao[dt][2] * inv, ao[dt][3] * inv);
    *(u32x2*)&ow[lr * 72 + dt * 16 + 4 * lg] = pk;
  }
  __syncthreads();
  int r = l >> 2, hc = l & 3;
  const u16* srow = sh + w * 1152 + r * 72 + hc * 16;
  u16* dst = O + ((size_t)(b * T_ + q0w + r)) * 768 + h * 64 + hc * 16;
  *(uint4*)&dst[0] = *(const uint4*)&srow[0];
  *(uint4*)&dst[8] = *(const uint4*)&srow[8];
}

// ---------------- launch ----------------

extern "C" void kernel_launch(void* const* d_in, const int* in_sizes, int n_in,
                              void* d_out, int out_size, void* d_ws, size_t ws_size,
                              hipStream_t stream) {
  const float* x     = (const float*)d_in[0];
  const float* Wqkv  = (const float*)d_in[1];
  const float* bqkv  = (const float*)d_in[2];
  const float* Wproj = (const float*)d_in[3];
  const float* bproj = (const float*)d_in[4];
  float* out = (float*)d_out;
  char* ws = (char*)d_ws;
  u16* xb     = (u16*)(ws);                // 4096*768*2      = 6291456
  u16* wqkvT  = (u16*)(ws + 6291456);      // 2304*768*2      = 3538944
  u16* wprojT = (u16*)(ws + 9830400);      // 768*768*2       = 1179648
  u16* qb     = (u16*)(ws + 11010048);     // 24*2048*64*2    = 6291456
  u16* kb     = (u16*)(ws + 17301504);     // 6291456
  u16* vpb    = (u16*)(ws + 23592960);     // 6291456
  u16* ob     = (u16*)(ws + 29884416);     // 6291456  (total 36175872)

  prep_kernel<<<5376, 256, 0, stream>>>(x, Wqkv, Wproj, xb, wqkvT, wprojT);
  gemm_kernel<0, 64><<<dim3(18, 64), 256, 0, stream>>>(xb, wqkvT, bqkv, qb, kb, vpb, nullptr);
  attn_kernel<<<768, 256, 0, stream>>>(qb, kb, vpb, ob);
  gemm_kernel<1, 64><<<dim3(6, 64), 256, 0, stream>>>(ob, wprojT, bproj, nullptr, nullptr, nullptr, out);
}

// Round 13
// 77.146 us; speedup vs baseline: 1.6491x; 1.0169x over previous
//
#include <hip/hip_runtime.h>
#include <stdint.h>

typedef short short8 __attribute__((ext_vector_type(8)));
typedef short short4v __attribute__((ext_vector_type(4)));
typedef float f32x4 __attribute__((ext_vector_type(4)));
typedef unsigned int u32x2 __attribute__((ext_vector_type(2)));
typedef unsigned int u32x4 __attribute__((ext_vector_type(4)));
typedef unsigned short u16;
typedef unsigned int u32;

#define T_ 2048
#define QK_SCALE 0.180336878f   // 0.125 * log2(e): softmax in log2 domain

__device__ inline u16 f2bf(float f) {
  unsigned u = __builtin_bit_cast(unsigned, f);
  u += 0x7fffu + ((u >> 16) & 1u);   // RNE; inputs finite
  return (u16)(u >> 16);
}

__device__ inline u32 cvt_pk_bf16(float lo, float hi) {
  u32 r;
  asm("v_cvt_pk_bf16_f32 %0, %1, %2" : "=v"(r) : "v"(lo), "v"(hi));
  return r;
}

__device__ inline f32x4 mfma_bf16(short8 a, short8 b, f32x4 c) {
  return __builtin_amdgcn_mfma_f32_16x16x32_bf16(a, b, c, 0, 0, 0);
}

// async global->LDS, 16B per lane; lds base must be wave-uniform
__device__ inline void gload16(const u16* g, u16* l) {
  __builtin_amdgcn_global_load_lds(
      (const __attribute__((address_space(1))) void*)g,
      (__attribute__((address_space(3))) void*)l, 16, 0, 0);
}

// ---------------- fused prep: convert x + transpose-convert both weights ----------------

__device__ inline void tile_transpose(const float* __restrict__ W, u16* __restrict__ Wt,
                                      int R, int Ccols, int c0, int r0, int t,
                                      float (*tile)[33]) {
  int tr = t >> 3, tc = (t & 7) * 4;
  float4 v = *(const float4*)&W[(size_t)(r0 + tr) * Ccols + c0 + tc];
  tile[tr][tc + 0] = v.x; tile[tr][tc + 1] = v.y;
  tile[tr][tc + 2] = v.z; tile[tr][tc + 3] = v.w;
  __syncthreads();
  short4v o;
#pragma unroll
  for (int i = 0; i < 4; ++i) o[i] = (short)f2bf(tile[tc + i][tr]);
  *(short4v*)&Wt[(size_t)(c0 + tr) * R + r0 + tc] = o;
}

__global__ __launch_bounds__(256) void prep_kernel(const float* __restrict__ x,
                                                   const float* __restrict__ Wqkv,
                                                   const float* __restrict__ Wproj,
                                                   u16* __restrict__ xb,
                                                   u16* __restrict__ wqkvT,
                                                   u16* __restrict__ wprojT) {
  __shared__ float tile[32][33];
  int bid = blockIdx.x, t = threadIdx.x;
  if (bid < 3072) {
    int i = (bid * 256 + t) * 4;
    float4 v = *(const float4*)&x[i];
    short4v o;
    o[0] = (short)f2bf(v.x); o[1] = (short)f2bf(v.y);
    o[2] = (short)f2bf(v.z); o[3] = (short)f2bf(v.w);
    *(short4v*)&xb[i] = o;
  } else if (bid < 3072 + 1728) {
    int t2 = bid - 3072;
    tile_transpose(Wqkv, wqkvT, 768, 2304, (t2 % 72) * 32, (t2 / 72) * 32, t, tile);
  } else {
    int t3 = bid - 4800;
    tile_transpose(Wproj, wprojT, 768, 768, (t3 % 24) * 32, (t3 / 24) * 32, t, tile);
  }
}

// ---------------- MTILE x 128 GEMM (gload_lds w16 + XOR swizzle + XCD chunking) ----------------

template <int MODE, int MTILE>
__global__ __launch_bounds__(256) void gemm_kernel(const u16* __restrict__ A,
                                                   const u16* __restrict__ Bt,
                                                   const float* __restrict__ bias,
                                                   u16* __restrict__ qb,
                                                   u16* __restrict__ kb,
                                                   u16* __restrict__ vpb,
                                                   float* __restrict__ out) {
  constexpr int MF = MTILE / 32;            // m-fragments per wave
  __shared__ u16 S[MTILE * 64 + 8192];      // As | Bs (reused as transpose buf)
  u16* As = S;
  u16* Bs = S + MTILE * 64;
  int tid = threadIdx.x, w = tid >> 6, l = tid & 63, lg = l >> 4, lr = l & 15;
  int nwg = gridDim.x * gridDim.y;
  int hw = blockIdx.y * gridDim.x + blockIdx.x;
  int logical = (hw & 7) * (nwg >> 3) + (hw >> 3);
  int n0 = (logical % gridDim.x) * 128, m0 = (logical / gridDim.x) * MTILE;
  int wm = (w >> 1) * (MTILE / 2), wn = (w & 1) * 64;
  f32x4 acc[MF][4] = {};
  int rsub = l >> 3;
  int sc = ((l & 7) ^ rsub) * 8;
  for (int kt = 0; kt < 12; ++kt) {
    int k0 = kt * 64;
    __syncthreads();
#pragma unroll
    for (int j = 0; j < MF; ++j) {
      int row = w * (MTILE / 4) + j * 8 + rsub;
      gload16(&A[(size_t)(m0 + row) * 768 + k0 + sc], &As[(w * MF + j) * 512]);
    }
#pragma unroll
    for (int j = 0; j < 4; ++j) {
      int row = w * 32 + j * 8 + rsub;
      gload16(&Bt[(size_t)(n0 + row) * 768 + k0 + sc], &Bs[(w * 4 + j) * 512]);
    }
    __syncthreads();
    short8 a[MF][2], b[4][2];
#pragma unroll
    for (int h = 0; h < 2; ++h) {
#pragma unroll
      for (int mf = 0; mf < MF; ++mf) {
        int cw = ((h * 4 + lg) ^ (lr & 7)) * 8;
        a[mf][h] = *(const short8*)&As[(wm + mf * 16 + lr) * 64 + cw];
      }
#pragma unroll
      for (int nf = 0; nf < 4; ++nf) {
        int cw = ((h * 4 + lg) ^ (lr & 7)) * 8;
        b[nf][h] = *(const short8*)&Bs[(wn + nf * 16 + lr) * 64 + cw];
      }
    }
#pragma unroll
    for (int h = 0; h < 2; ++h)
#pragma unroll
      for (int mf = 0; mf < MF; ++mf)
#pragma unroll
        for (int nf = 0; nf < 4; ++nf)
          acc[mf][nf] = mfma_bf16(a[mf][h], b[nf][h], acc[mf][nf]);
  }

  if constexpr (MODE == 0) {
    int sec = (n0 >= 1536) ? 2 : (n0 >= 768 ? 1 : 0);
    int ncol0 = n0 - sec * 768;
    if (sec < 2) {
#pragma unroll
      for (int nf = 0; nf < 4; ++nf) {
        int nn = wn + nf * 16 + lr;
        float bv = bias[n0 + nn];
        int c = ncol0 + nn;
        int hh = c >> 6, d = c & 63;
#pragma unroll
        for (int mf = 0; mf < MF; ++mf)
#pragma unroll
          for (int rr = 0; rr < 4; ++rr) {
            int m = m0 + wm + mf * 16 + 4 * lg + rr;
            int bb = m >> 11, tt = m & 2047;
            int bh = bb * 12 + hh;
            float v = acc[mf][nf][rr] + bv;
            if (sec == 0) qb[((size_t)bh * T_ + tt) * 64 + d] = f2bf(v * QK_SCALE);
            else          kb[((size_t)bh * T_ + tt) * 64 + d] = f2bf(v);
          }
      }
    } else {
      // V^T: transpose in LDS (p5 key-permutation folded into column), coalesced rows out.
      __syncthreads();
#pragma unroll
      for (int nf = 0; nf < 4; ++nf) {
        int row = wn + nf * 16 + lr;
        float bv = bias[n0 + row];
        int swz = (row & 7) << 3;
#pragma unroll
        for (int mf = 0; mf < MF; ++mf) {
          int pcol0 = wm + (mf >> 1) * 32 + 8 * lg + 4 * (mf & 1);
          u32x2 pk;
          pk[0] = cvt_pk_bf16(acc[mf][nf][0] + bv, acc[mf][nf][1] + bv);
          pk[1] = cvt_pk_bf16(acc[mf][nf][2] + bv, acc[mf][nf][3] + bv);
          *(u32x2*)&S[row * MTILE + (pcol0 ^ swz)] = pk;
        }
      }
      __syncthreads();
      constexpr int CPT = MTILE / 2;
      int rowo = tid >> 1, half = tid & 1;
      int c = ncol0 + rowo;
      int d = c & 63, hh = c >> 6;
      int bh = (m0 >> 11) * 12 + hh;
      u16* dst = vpb + ((size_t)bh * 64 + d) * T_ + (m0 & 2047) + half * CPT;
      int swzo = (rowo & 7) << 3;
#pragma unroll
      for (int i = 0; i < CPT / 8; ++i) {
        int col = half * CPT + i * 8;
        uint4 v = *(const uint4*)&S[rowo * MTILE + (col ^ swzo)];
        *(uint4*)&dst[i * 8] = v;
      }
    }
  } else {
#pragma unroll
    for (int nf = 0; nf < 4; ++nf) {
      int n = n0 + wn + nf * 16 + lr;
      float bv = bias[n];
#pragma unroll
      for (int mf = 0; mf < MF; ++mf)
#pragma unroll
        for (int rr = 0; rr < 4; ++rr) {
          int m = m0 + wm + mf * 16 + 4 * lg + rr;
          out[(size_t)m * 768 + n] = acc[mf][nf][rr] + bv;
        }
    }
  }
}

// ---------------- flash attention (8 waves, key-split, no-max softmax) ----------------
// Q,K: [BH][T][64] bf16 (Q pre-scaled by 0.125*log2e), Vp: [BH][64][T] bf16
// (key-permuted), O: [B*T][768] bf16. Block = 64 q-rows, 768 blocks (3/CU).
// Wave (i,j): i = q-quarter (16 rows), j = key half (32 keys). No-max softmax
// makes PV partials over key-halves ADDITIVE -> private (ao,lrow) per wave,
// merged once via LDS at the end. 24 waves/CU; per-wave chain halved vs R12.

__global__ __launch_bounds__(512) void attn_kernel(const u16* __restrict__ Q,
                                                   const u16* __restrict__ K,
                                                   const u16* __restrict__ Vp,
                                                   u16* __restrict__ O) {
  __shared__ u16 sh[16384];  // K dbuf 2x4096, V dbuf 2x4096 (swizzled linear)
  int tid = threadIdx.x;
  int w = tid >> 6, l = tid & 63, lg = l >> 4, lr = l & 15;
  int i = w >> 1, j = w & 1;
  int idx = blockIdx.x;
  int head = idx % 24;                 // 24 % 8 == 0: same head -> same XCD (L2 reuse)
  int qblk = 31 - idx / 24;            // big-work blocks dispatch first
  int b = head / 12, h = head % 12;
  int q0 = qblk * 64;
  int q0w = q0 + i * 16;               // this wave's 16 q-rows
  const u16* Qb = Q + (size_t)head * T_ * 64;
  const u16* Kb = K + (size_t)head * T_ * 64;
  const u16* Vb = Vp + (size_t)head * 64 * T_;

  short8 qf0 = *(const short8*)&Qb[(size_t)(q0w + lr) * 64 + 8 * lg];
  short8 qf1 = *(const short8*)&Qb[(size_t)(q0w + lr) * 64 + 32 + 8 * lg];

  f32x4 ao[4] = {};
  float lrow = 0.f;                    // per-lane partial (this wave's key half)
  int rsub = l >> 3;
  int scs = ((l & 7) ^ rsub) * 8;
  const int nt = qblk + 1;

  // prologue: stage tile 0 (8 waves x {1 K-row-block + 1 V-row-block})
  {
    int row = w * 8 + rsub;
    gload16(&Kb[(size_t)row * 64 + scs], &sh[w * 512]);
    gload16(&Vb[(size_t)row * T_ + scs], &sh[8192 + w * 512]);
  }
  __syncthreads();

  for (int t = 0; t < nt; ++t) {
    int cur = t & 1;
    int k0 = t * 64;
    if (t + 1 < nt) {
      int k1 = k0 + 64;
      int row = w * 8 + rsub;
      gload16(&Kb[(size_t)(k1 + row) * 64 + scs], &sh[(cur ^ 1) * 4096 + w * 512]);
      gload16(&Vb[(size_t)row * T_ + k1 + scs], &sh[8192 + (cur ^ 1) * 4096 + w * 512]);
    }
    if (k0 + 32 * j <= q0w + 15) {     // wave-uniform: skip if this key-half is all-masked
      const u16* ks = sh + cur * 4096;
      const u16* vs = sh + 8192 + cur * 4096;
      // this wave's half: keys [k0+32j, k0+32j+32), kg groups {2j, 2j+1}
      short8 ka0[2], ka1[2], va[4];
#pragma unroll
      for (int g = 0; g < 2; ++g) {
        int kg = 2 * j + g;
        ka0[g] = *(const short8*)&ks[(kg * 16 + lr) * 64 + ((lg ^ (lr & 7)) * 8)];
        ka1[g] = *(const short8*)&ks[(kg * 16 + lr) * 64 + (((4 + lg) ^ (lr & 7)) * 8)];
      }
#pragma unroll
      for (int dt = 0; dt < 4; ++dt)
        va[dt] = *(const short8*)&vs[(dt * 16 + lr) * 64 + (((4 * j + lg) ^ (lr & 7)) * 8)];
      f32x4 sm[2];
      __builtin_amdgcn_s_setprio(1);
#pragma unroll
      for (int g = 0; g < 2; ++g) {
        f32x4 z = {};
        z = mfma_bf16(ka0[g], qf0, z);
        z = mfma_bf16(ka1[g], qf1, z);
        sm[g] = z;
      }
      __builtin_amdgcn_s_setprio(0);
      float sv[8];
      float ps = 0.f;
      bool needmask = (t == nt - 1) && (32 * j + 31 > 16 * i);
      if (needmask) {
        int qa = q0w + lr;
#pragma unroll
        for (int g = 0; g < 2; ++g)
#pragma unroll
          for (int rr = 0; rr < 4; ++rr) {
            int key = k0 + (2 * j + g) * 16 + 4 * lg + rr;
            float x = (key <= qa) ? sm[g][rr] : -1e30f;
            float p = __builtin_amdgcn_exp2f(x);   // exp2(-1e30) = 0
            sv[g * 4 + rr] = p;
            ps += p;
          }
      } else {
#pragma unroll
        for (int g = 0; g < 2; ++g)
#pragma unroll
          for (int rr = 0; rr < 4; ++rr) {
            float p = __builtin_amdgcn_exp2f(sm[g][rr]);
            sv[g * 4 + rr] = p;
            ps += p;
          }
      }
      lrow += ps;
      u32x4 uu;
      uu[0] = cvt_pk_bf16(sv[0], sv[1]);
      uu[1] = cvt_pk_bf16(sv[2], sv[3]);
      uu[2] = cvt_pk_bf16(sv[4], sv[5]);
      uu[3] = cvt_pk_bf16(sv[6], sv[7]);
      short8 pb = __builtin_bit_cast(short8, uu);
      __builtin_amdgcn_s_setprio(1);
#pragma unroll
      for (int dt = 0; dt < 4; ++dt)
        ao[dt] = mfma_bf16(va[dt], pb, ao[dt]);
      __builtin_amdgcn_s_setprio(0);
    }
    __syncthreads();
  }

  // reduce partial row-sums within wave (lanes {l, l^16, l^32, l^48} share q = lr)
  lrow += __shfl_xor(lrow, 16);
  lrow += __shfl_xor(lrow, 32);

  // merge key-half partials: j=1 writes (ao, lrow) to LDS; j=0 adds.
  float* aoL = (float*)sh;                    // [4][64][16] f32 = 16 KB
  float* lrL = (float*)(sh + 8192);           // [4][64] f32 = 1 KB
  if (j == 1) {
#pragma unroll
    for (int dt = 0; dt < 4; ++dt)
      *(f32x4*)&aoL[(i * 64 + l) * 16 + dt * 4] = ao[dt];
    lrL[i * 64 + l] = lrow;
  }
  __syncthreads();
  if (j == 0) {
#pragma unroll
    for (int dt = 0; dt < 4; ++dt)
      ao[dt] += *(const f32x4*)&aoL[(i * 64 + l) * 16 + dt * 4];
    lrow += lrL[i * 64 + l];
    // epilogue: normalize + transpose O^T(d,q) -> O(q,d) via per-i LDS region
    u16* ow = sh + 9216 + i * 1152;   // [16][72]
    float inv = 1.0f / lrow;
#pragma unroll
    for (int dt = 0; dt < 4; ++dt) {
      u32x2 pk;
      pk[0] = cvt_pk_bf16(ao[dt][0] * inv, ao[dt][1] * inv);
      pk[1] = cvt_pk_bf16(ao[dt][2] * inv, ao[dt][3] * inv);
      *(u32x2*)&ow[lr * 72 + dt * 16 + 4 * lg] = pk;
    }
    asm volatile("s_waitcnt lgkmcnt(0)" ::: "memory");  // wave-local write->read
    int r = l >> 2, hc = l & 3;
    const u16* srow = sh + 9216 + i * 1152 + r * 72 + hc * 16;
    u16* dst = O + ((size_t)(b * T_ + q0w + r)) * 768 + h * 64 + hc * 16;
    *(uint4*)&dst[0] = *(const uint4*)&srow[0];
    *(uint4*)&dst[8] = *(const uint4*)&srow[8];
  }
}

// ---------------- launch ----------------

extern "C" void kernel_launch(void* const* d_in, const int* in_sizes, int n_in,
                              void* d_out, int out_size, void* d_ws, size_t ws_size,
                              hipStream_t stream) {
  const float* x     = (const float*)d_in[0];
  const float* Wqkv  = (const float*)d_in[1];
  const float* bqkv  = (const float*)d_in[2];
  const float* Wproj = (const float*)d_in[3];
  const float* bproj = (const float*)d_in[4];
  float* out = (float*)d_out;
  char* ws = (char*)d_ws;
  u16* xb     = (u16*)(ws);                // 4096*768*2      = 6291456
  u16* wqkvT  = (u16*)(ws + 6291456);      // 2304*768*2      = 3538944
  u16* wprojT = (u16*)(ws + 9830400);      // 768*768*2       = 1179648
  u16* qb     = (u16*)(ws + 11010048);     // 24*2048*64*2    = 6291456
  u16* kb     = (u16*)(ws + 17301504);     // 6291456
  u16* vpb    = (u16*)(ws + 23592960);     // 6291456
  u16* ob     = (u16*)(ws + 29884416);     // 6291456  (total 36175872)

  prep_kernel<<<5376, 256, 0, stream>>>(x, Wqkv, Wproj, xb, wqkvT, wprojT);
  gemm_kernel<0, 64><<<dim3(18, 64), 256, 0, stream>>>(xb, wqkvT, bqkv, qb, kb, vpb, nullptr);
  attn_kernel<<<768, 512, 0, stream>>>(qb, kb, vpb, ob);
  gemm_kernel<1, 64><<<dim3(6, 64), 256, 0, stream>>>(ob, wprojT, bproj, nullptr, nullptr, nullptr, out);
}

// Round 14
// 76.746 us; speedup vs baseline: 1.6577x; 1.0052x over previous
//
#include <hip/hip_runtime.h>
#include <stdint.h>

typedef short short8 __attribute__((ext_vector_type(8)));
typedef short short4v __attribute__((ext_vector_type(4)));
typedef float f32x4 __attribute__((ext_vector_type(4)));
typedef unsigned int u32x2 __attribute__((ext_vector_type(2)));
typedef unsigned int u32x4 __attribute__((ext_vector_type(4)));
typedef unsigned short u16;
typedef unsigned int u32;

#define T_ 2048
#define QK_SCALE 0.180336878f   // 0.125 * log2(e): softmax in log2 domain

__device__ inline u16 f2bf(float f) {
  unsigned u = __builtin_bit_cast(unsigned, f);
  u += 0x7fffu + ((u >> 16) & 1u);   // RNE; inputs finite
  return (u16)(u >> 16);
}

__device__ inline u32 cvt_pk_bf16(float lo, float hi) {
  u32 r;
  asm("v_cvt_pk_bf16_f32 %0, %1, %2" : "=v"(r) : "v"(lo), "v"(hi));
  return r;
}

__device__ inline f32x4 mfma_bf16(short8 a, short8 b, f32x4 c) {
  return __builtin_amdgcn_mfma_f32_16x16x32_bf16(a, b, c, 0, 0, 0);
}

// async global->LDS, 16B per lane; lds base must be wave-uniform
__device__ inline void gload16(const u16* g, u16* l) {
  __builtin_amdgcn_global_load_lds(
      (const __attribute__((address_space(1))) void*)g,
      (__attribute__((address_space(3))) void*)l, 16, 0, 0);
}

// ---------------- fused prep: convert x + transpose-convert both weights ----------------

__device__ inline void tile_transpose(const float* __restrict__ W, u16* __restrict__ Wt,
                                      int R, int Ccols, int c0, int r0, int t,
                                      float (*tile)[33]) {
  int tr = t >> 3, tc = (t & 7) * 4;
  float4 v = *(const float4*)&W[(size_t)(r0 + tr) * Ccols + c0 + tc];
  tile[tr][tc + 0] = v.x; tile[tr][tc + 1] = v.y;
  tile[tr][tc + 2] = v.z; tile[tr][tc + 3] = v.w;
  __syncthreads();
  short4v o;
#pragma unroll
  for (int i = 0; i < 4; ++i) o[i] = (short)f2bf(tile[tc + i][tr]);
  *(short4v*)&Wt[(size_t)(c0 + tr) * R + r0 + tc] = o;
}

__global__ __launch_bounds__(256) void prep_kernel(const float* __restrict__ x,
                                                   const float* __restrict__ Wqkv,
                                                   const float* __restrict__ Wproj,
                                                   u16* __restrict__ xb,
                                                   u16* __restrict__ wqkvT,
                                                   u16* __restrict__ wprojT) {
  __shared__ float tile[32][33];
  int bid = blockIdx.x, t = threadIdx.x;
  if (bid < 3072) {
    int i = (bid * 256 + t) * 4;
    float4 v = *(const float4*)&x[i];
    short4v o;
    o[0] = (short)f2bf(v.x); o[1] = (short)f2bf(v.y);
    o[2] = (short)f2bf(v.z); o[3] = (short)f2bf(v.w);
    *(short4v*)&xb[i] = o;
  } else if (bid < 3072 + 1728) {
    int t2 = bid - 3072;
    tile_transpose(Wqkv, wqkvT, 768, 2304, (t2 % 72) * 32, (t2 / 72) * 32, t, tile);
  } else {
    int t3 = bid - 4800;
    tile_transpose(Wproj, wprojT, 768, 768, (t3 % 24) * 32, (t3 / 24) * 32, t, tile);
  }
}

// ---------------- MTILE x 128 GEMM (gload_lds w16 + XOR swizzle + XCD chunking) ----------------
// MODE 0 (MTILE=64): qkv epilogue; MODE 1 (MTILE=32): proj epilogue, 3 blocks/CU.

template <int MODE, int MTILE>
__global__ __launch_bounds__(256) void gemm_kernel(const u16* __restrict__ A,
                                                   const u16* __restrict__ Bt,
                                                   const float* __restrict__ bias,
                                                   u16* __restrict__ qb,
                                                   u16* __restrict__ kb,
                                                   u16* __restrict__ vpb,
                                                   float* __restrict__ out) {
  constexpr int MF = MTILE / 32;            // m-fragments per wave
  __shared__ u16 S[MTILE * 64 + 8192];      // As | Bs (reused as transpose buf)
  u16* As = S;
  u16* Bs = S + MTILE * 64;
  int tid = threadIdx.x, w = tid >> 6, l = tid & 63, lg = l >> 4, lr = l & 15;
  int nwg = gridDim.x * gridDim.y;
  int hw = blockIdx.y * gridDim.x + blockIdx.x;
  int logical = (hw & 7) * (nwg >> 3) + (hw >> 3);
  int n0 = (logical % gridDim.x) * 128, m0 = (logical / gridDim.x) * MTILE;
  int wm = (w >> 1) * (MTILE / 2), wn = (w & 1) * 64;
  f32x4 acc[MF][4] = {};
  int rsub = l >> 3;
  int sc = ((l & 7) ^ rsub) * 8;
  for (int kt = 0; kt < 12; ++kt) {
    int k0 = kt * 64;
    __syncthreads();
#pragma unroll
    for (int j = 0; j < MF; ++j) {
      int row = w * (MTILE / 4) + j * 8 + rsub;
      gload16(&A[(size_t)(m0 + row) * 768 + k0 + sc], &As[(w * MF + j) * 512]);
    }
#pragma unroll
    for (int j = 0; j < 4; ++j) {
      int row = w * 32 + j * 8 + rsub;
      gload16(&Bt[(size_t)(n0 + row) * 768 + k0 + sc], &Bs[(w * 4 + j) * 512]);
    }
    __syncthreads();
    short8 a[MF][2], b[4][2];
#pragma unroll
    for (int h = 0; h < 2; ++h) {
#pragma unroll
      for (int mf = 0; mf < MF; ++mf) {
        int cw = ((h * 4 + lg) ^ (lr & 7)) * 8;
        a[mf][h] = *(const short8*)&As[(wm + mf * 16 + lr) * 64 + cw];
      }
#pragma unroll
      for (int nf = 0; nf < 4; ++nf) {
        int cw = ((h * 4 + lg) ^ (lr & 7)) * 8;
        b[nf][h] = *(const short8*)&Bs[(wn + nf * 16 + lr) * 64 + cw];
      }
    }
#pragma unroll
    for (int h = 0; h < 2; ++h)
#pragma unroll
      for (int mf = 0; mf < MF; ++mf)
#pragma unroll
        for (int nf = 0; nf < 4; ++nf)
          acc[mf][nf] = mfma_bf16(a[mf][h], b[nf][h], acc[mf][nf]);
  }

  if constexpr (MODE == 0) {
    int sec = (n0 >= 1536) ? 2 : (n0 >= 768 ? 1 : 0);
    int ncol0 = n0 - sec * 768;
    if (sec < 2) {
#pragma unroll
      for (int nf = 0; nf < 4; ++nf) {
        int nn = wn + nf * 16 + lr;
        float bv = bias[n0 + nn];
        int c = ncol0 + nn;
        int hh = c >> 6, d = c & 63;
#pragma unroll
        for (int mf = 0; mf < MF; ++mf)
#pragma unroll
          for (int rr = 0; rr < 4; ++rr) {
            int m = m0 + wm + mf * 16 + 4 * lg + rr;
            int bb = m >> 11, tt = m & 2047;
            int bh = bb * 12 + hh;
            float v = acc[mf][nf][rr] + bv;
            if (sec == 0) qb[((size_t)bh * T_ + tt) * 64 + d] = f2bf(v * QK_SCALE);
            else          kb[((size_t)bh * T_ + tt) * 64 + d] = f2bf(v);
          }
      }
    } else {
      // V^T: transpose in LDS (p5 key-permutation folded into column), coalesced rows out.
      __syncthreads();
#pragma unroll
      for (int nf = 0; nf < 4; ++nf) {
        int row = wn + nf * 16 + lr;
        float bv = bias[n0 + row];
        int swz = (row & 7) << 3;
#pragma unroll
        for (int mf = 0; mf < MF; ++mf) {
          int pcol0 = wm + (mf >> 1) * 32 + 8 * lg + 4 * (mf & 1);
          u32x2 pk;
          pk[0] = cvt_pk_bf16(acc[mf][nf][0] + bv, acc[mf][nf][1] + bv);
          pk[1] = cvt_pk_bf16(acc[mf][nf][2] + bv, acc[mf][nf][3] + bv);
          *(u32x2*)&S[row * MTILE + (pcol0 ^ swz)] = pk;
        }
      }
      __syncthreads();
      constexpr int CPT = MTILE / 2;
      int rowo = tid >> 1, half = tid & 1;
      int c = ncol0 + rowo;
      int d = c & 63, hh = c >> 6;
      int bh = (m0 >> 11) * 12 + hh;
      u16* dst = vpb + ((size_t)bh * 64 + d) * T_ + (m0 & 2047) + half * CPT;
      int swzo = (rowo & 7) << 3;
#pragma unroll
      for (int i = 0; i < CPT / 8; ++i) {
        int col = half * CPT + i * 8;
        uint4 v = *(const uint4*)&S[rowo * MTILE + (col ^ swzo)];
        *(uint4*)&dst[i * 8] = v;
      }
    }
  } else {
#pragma unroll
    for (int nf = 0; nf < 4; ++nf) {
      int n = n0 + wn + nf * 16 + lr;
      float bv = bias[n];
#pragma unroll
      for (int mf = 0; mf < MF; ++mf)
#pragma unroll
        for (int rr = 0; rr < 4; ++rr) {
          int m = m0 + wm + mf * 16 + 4 * lg + rr;
          out[(size_t)m * 768 + n] = acc[mf][nf][rr] + bv;
        }
    }
  }
}

// ---------------- flash attention (8 waves, key-split, no-max softmax) ----------------
// Identical to R13 (verified 77.1 us total).

__global__ __launch_bounds__(512) void attn_kernel(const u16* __restrict__ Q,
                                                   const u16* __restrict__ K,
                                                   const u16* __restrict__ Vp,
                                                   u16* __restrict__ O) {
  __shared__ u16 sh[16384];  // K dbuf 2x4096, V dbuf 2x4096 (swizzled linear)
  int tid = threadIdx.x;
  int w = tid >> 6, l = tid & 63, lg = l >> 4, lr = l & 15;
  int i = w >> 1, j = w & 1;
  int idx = blockIdx.x;
  int head = idx % 24;                 // 24 % 8 == 0: same head -> same XCD (L2 reuse)
  int qblk = 31 - idx / 24;            // big-work blocks dispatch first
  int b = head / 12, h = head % 12;
  int q0 = qblk * 64;
  int q0w = q0 + i * 16;               // this wave's 16 q-rows
  const u16* Qb = Q + (size_t)head * T_ * 64;
  const u16* Kb = K + (size_t)head * T_ * 64;
  const u16* Vb = Vp + (size_t)head * 64 * T_;

  short8 qf0 = *(const short8*)&Qb[(size_t)(q0w + lr) * 64 + 8 * lg];
  short8 qf1 = *(const short8*)&Qb[(size_t)(q0w + lr) * 64 + 32 + 8 * lg];

  f32x4 ao[4] = {};
  float lrow = 0.f;                    // per-lane partial (this wave's key half)
  int rsub = l >> 3;
  int scs = ((l & 7) ^ rsub) * 8;
  const int nt = qblk + 1;

  // prologue: stage tile 0 (8 waves x {1 K-row-block + 1 V-row-block})
  {
    int row = w * 8 + rsub;
    gload16(&Kb[(size_t)row * 64 + scs], &sh[w * 512]);
    gload16(&Vb[(size_t)row * T_ + scs], &sh[8192 + w * 512]);
  }
  __syncthreads();

  for (int t = 0; t < nt; ++t) {
    int cur = t & 1;
    int k0 = t * 64;
    if (t + 1 < nt) {
      int k1 = k0 + 64;
      int row = w * 8 + rsub;
      gload16(&Kb[(size_t)(k1 + row) * 64 + scs], &sh[(cur ^ 1) * 4096 + w * 512]);
      gload16(&Vb[(size_t)row * T_ + k1 + scs], &sh[8192 + (cur ^ 1) * 4096 + w * 512]);
    }
    if (k0 + 32 * j <= q0w + 15) {     // wave-uniform: skip if this key-half is all-masked
      const u16* ks = sh + cur * 4096;
      const u16* vs = sh + 8192 + cur * 4096;
      short8 ka0[2], ka1[2], va[4];
#pragma unroll
      for (int g = 0; g < 2; ++g) {
        int kg = 2 * j + g;
        ka0[g] = *(const short8*)&ks[(kg * 16 + lr) * 64 + ((lg ^ (lr & 7)) * 8)];
        ka1[g] = *(const short8*)&ks[(kg * 16 + lr) * 64 + (((4 + lg) ^ (lr & 7)) * 8)];
      }
#pragma unroll
      for (int dt = 0; dt < 4; ++dt)
        va[dt] = *(const short8*)&vs[(dt * 16 + lr) * 64 + (((4 * j + lg) ^ (lr & 7)) * 8)];
      f32x4 sm[2];
      __builtin_amdgcn_s_setprio(1);
#pragma unroll
      for (int g = 0; g < 2; ++g) {
        f32x4 z = {};
        z = mfma_bf16(ka0[g], qf0, z);
        z = mfma_bf16(ka1[g], qf1, z);
        sm[g] = z;
      }
      __builtin_amdgcn_s_setprio(0);
      float sv[8];
      float ps = 0.f;
      bool needmask = (t == nt - 1) && (32 * j + 31 > 16 * i);
      if (needmask) {
        int qa = q0w + lr;
#pragma unroll
        for (int g = 0; g < 2; ++g)
#pragma unroll
          for (int rr = 0; rr < 4; ++rr) {
            int key = k0 + (2 * j + g) * 16 + 4 * lg + rr;
            float x = (key <= qa) ? sm[g][rr] : -1e30f;
            float p = __builtin_amdgcn_exp2f(x);   // exp2(-1e30) = 0
            sv[g * 4 + rr] = p;
            ps += p;
          }
      } else {
#pragma unroll
        for (int g = 0; g < 2; ++g)
#pragma unroll
          for (int rr = 0; rr < 4; ++rr) {
            float p = __builtin_amdgcn_exp2f(sm[g][rr]);
            sv[g * 4 + rr] = p;
            ps += p;
          }
      }
      lrow += ps;
      u32x4 uu;
      uu[0] = cvt_pk_bf16(sv[0], sv[1]);
      uu[1] = cvt_pk_bf16(sv[2], sv[3]);
      uu[2] = cvt_pk_bf16(sv[4], sv[5]);
      uu[3] = cvt_pk_bf16(sv[6], sv[7]);
      short8 pb = __builtin_bit_cast(short8, uu);
      __builtin_amdgcn_s_setprio(1);
#pragma unroll
      for (int dt = 0; dt < 4; ++dt)
        ao[dt] = mfma_bf16(va[dt], pb, ao[dt]);
      __builtin_amdgcn_s_setprio(0);
    }
    __syncthreads();
  }

  // reduce partial row-sums within wave (lanes {l, l^16, l^32, l^48} share q = lr)
  lrow += __shfl_xor(lrow, 16);
  lrow += __shfl_xor(lrow, 32);

  // merge key-half partials: j=1 writes (ao, lrow) to LDS; j=0 adds.
  float* aoL = (float*)sh;                    // [4][64][16] f32 = 16 KB
  float* lrL = (float*)(sh + 8192);           // [4][64] f32 = 1 KB
  if (j == 1) {
#pragma unroll
    for (int dt = 0; dt < 4; ++dt)
      *(f32x4*)&aoL[(i * 64 + l) * 16 + dt * 4] = ao[dt];
    lrL[i * 64 + l] = lrow;
  }
  __syncthreads();
  if (j == 0) {
#pragma unroll
    for (int dt = 0; dt < 4; ++dt)
      ao[dt] += *(const f32x4*)&aoL[(i * 64 + l) * 16 + dt * 4];
    lrow += lrL[i * 64 + l];
    // epilogue: normalize + transpose O^T(d,q) -> O(q,d) via per-i LDS region
    u16* ow = sh + 9216 + i * 1152;   // [16][72]
    float inv = 1.0f / lrow;
#pragma unroll
    for (int dt = 0; dt < 4; ++dt) {
      u32x2 pk;
      pk[0] = cvt_pk_bf16(ao[dt][0] * inv, ao[dt][1] * inv);
      pk[1] = cvt_pk_bf16(ao[dt][2] * inv, ao[dt][3] * inv);
      *(u32x2*)&ow[lr * 72 + dt * 16 + 4 * lg] = pk;
    }
    asm volatile("s_waitcnt lgkmcnt(0)" ::: "memory");  // wave-local write->read
    int r = l >> 2, hc = l & 3;
    const u16* srow = sh + 9216 + i * 1152 + r * 72 + hc * 16;
    u16* dst = O + ((size_t)(b * T_ + q0w + r)) * 768 + h * 64 + hc * 16;
    *(uint4*)&dst[0] = *(const uint4*)&srow[0];
    *(uint4*)&dst[8] = *(const uint4*)&srow[8];
  }
}

// ---------------- launch ----------------

extern "C" void kernel_launch(void* const* d_in, const int* in_sizes, int n_in,
                              void* d_out, int out_size, void* d_ws, size_t ws_size,
                              hipStream_t stream) {
  const float* x     = (const float*)d_in[0];
  const float* Wqkv  = (const float*)d_in[1];
  const float* bqkv  = (const float*)d_in[2];
  const float* Wproj = (const float*)d_in[3];
  const float* bproj = (const float*)d_in[4];
  float* out = (float*)d_out;
  char* ws = (char*)d_ws;
  u16* xb     = (u16*)(ws);                // 4096*768*2      = 6291456
  u16* wqkvT  = (u16*)(ws + 6291456);      // 2304*768*2      = 3538944
  u16* wprojT = (u16*)(ws + 9830400);      // 768*768*2       = 1179648
  u16* qb     = (u16*)(ws + 11010048);     // 24*2048*64*2    = 6291456
  u16* kb     = (u16*)(ws + 17301504);     // 6291456
  u16* vpb    = (u16*)(ws + 23592960);     // 6291456
  u16* ob     = (u16*)(ws + 29884416);     // 6291456  (total 36175872)

  prep_kernel<<<5376, 256, 0, stream>>>(x, Wqkv, Wproj, xb, wqkvT, wprojT);
  gemm_kernel<0, 64><<<dim3(18, 64), 256, 0, stream>>>(xb, wqkvT, bqkv, qb, kb, vpb, nullptr);
  attn_kernel<<<768, 512, 0, stream>>>(qb, kb, vpb, ob);
  gemm_kernel<1, 32><<<dim3(6, 128), 256, 0, stream>>>(ob, wprojT, bproj, nullptr, nullptr, nullptr, out);
}

// Round 15
// 73.959 us; speedup vs baseline: 1.7202x; 1.0377x over previous
//
#include <hip/hip_runtime.h>
#include <stdint.h>

typedef short short8 __attribute__((ext_vector_type(8)));
typedef short short4v __attribute__((ext_vector_type(4)));
typedef float f32x4 __attribute__((ext_vector_type(4)));
typedef unsigned int u32x2 __attribute__((ext_vector_type(2)));
typedef unsigned int u32x4 __attribute__((ext_vector_type(4)));
typedef unsigned short u16;
typedef unsigned int u32;

#define T_ 2048
#define QK_SCALE 0.180336878f   // 0.125 * log2(e): softmax in log2 domain

__device__ inline u16 f2bf(float f) {
  unsigned u = __builtin_bit_cast(unsigned, f);
  u += 0x7fffu + ((u >> 16) & 1u);   // RNE; inputs finite
  return (u16)(u >> 16);
}

__device__ inline u32 cvt_pk_bf16(float lo, float hi) {
  u32 r;
  asm("v_cvt_pk_bf16_f32 %0, %1, %2" : "=v"(r) : "v"(lo), "v"(hi));
  return r;
}

__device__ inline f32x4 mfma_bf16(short8 a, short8 b, f32x4 c) {
  return __builtin_amdgcn_mfma_f32_16x16x32_bf16(a, b, c, 0, 0, 0);
}

// async global->LDS, 16B per lane; lds base must be wave-uniform
__device__ inline void gload16(const u16* g, u16* l) {
  __builtin_amdgcn_global_load_lds(
      (const __attribute__((address_space(1))) void*)g,
      (__attribute__((address_space(3))) void*)l, 16, 0, 0);
}

// ---------------- fused prep: convert x + transpose-convert both weights ----------------

__device__ inline void tile_transpose(const float* __restrict__ W, u16* __restrict__ Wt,
                                      int R, int Ccols, int c0, int r0, int t,
                                      float (*tile)[33]) {
  int tr = t >> 3, tc = (t & 7) * 4;
  float4 v = *(const float4*)&W[(size_t)(r0 + tr) * Ccols + c0 + tc];
  tile[tr][tc + 0] = v.x; tile[tr][tc + 1] = v.y;
  tile[tr][tc + 2] = v.z; tile[tr][tc + 3] = v.w;
  __syncthreads();
  short4v o;
#pragma unroll
  for (int i = 0; i < 4; ++i) o[i] = (short)f2bf(tile[tc + i][tr]);
  *(short4v*)&Wt[(size_t)(c0 + tr) * R + r0 + tc] = o;
}

__global__ __launch_bounds__(256) void prep_kernel(const float* __restrict__ x,
                                                   const float* __restrict__ Wqkv,
                                                   const float* __restrict__ Wproj,
                                                   u16* __restrict__ xb,
                                                   u16* __restrict__ wqkvT,
                                                   u16* __restrict__ wprojT) {
  __shared__ float tile[32][33];
  int bid = blockIdx.x, t = threadIdx.x;
  if (bid < 3072) {
    int i = (bid * 256 + t) * 4;
    float4 v = *(const float4*)&x[i];
    short4v o;
    o[0] = (short)f2bf(v.x); o[1] = (short)f2bf(v.y);
    o[2] = (short)f2bf(v.z); o[3] = (short)f2bf(v.w);
    *(short4v*)&xb[i] = o;
  } else if (bid < 3072 + 1728) {
    int t2 = bid - 3072;
    tile_transpose(Wqkv, wqkvT, 768, 2304, (t2 % 72) * 32, (t2 / 72) * 32, t, tile);
  } else {
    int t3 = bid - 4800;
    tile_transpose(Wproj, wprojT, 768, 768, (t3 % 24) * 32, (t3 / 24) * 32, t, tile);
  }
}

// ---------------- MTILE x 128 GEMM (gload_lds w16 + XOR swizzle + XCD chunking) ----------------
// MODE 0 (MTILE=64): qkv epilogue; MODE 1 (MTILE=32): proj epilogue.

template <int MODE, int MTILE>
__global__ __launch_bounds__(256) void gemm_kernel(const u16* __restrict__ A,
                                                   const u16* __restrict__ Bt,
                                                   const float* __restrict__ bias,
                                                   u16* __restrict__ qb,
                                                   u16* __restrict__ kb,
                                                   u16* __restrict__ vpb,
                                                   float* __restrict__ out) {
  constexpr int MF = MTILE / 32;            // m-fragments per wave
  __shared__ u16 S[MTILE * 64 + 8192];      // As | Bs (reused as transpose buf)
  u16* As = S;
  u16* Bs = S + MTILE * 64;
  int tid = threadIdx.x, w = tid >> 6, l = tid & 63, lg = l >> 4, lr = l & 15;
  int nwg = gridDim.x * gridDim.y;
  int hw = blockIdx.y * gridDim.x + blockIdx.x;
  int logical = (hw & 7) * (nwg >> 3) + (hw >> 3);
  int n0 = (logical % gridDim.x) * 128, m0 = (logical / gridDim.x) * MTILE;
  int wm = (w >> 1) * (MTILE / 2), wn = (w & 1) * 64;
  f32x4 acc[MF][4] = {};
  int rsub = l >> 3;
  int sc = ((l & 7) ^ rsub) * 8;
  for (int kt = 0; kt < 12; ++kt) {
    int k0 = kt * 64;
    __syncthreads();
#pragma unroll
    for (int j = 0; j < MF; ++j) {
      int row = w * (MTILE / 4) + j * 8 + rsub;
      gload16(&A[(size_t)(m0 + row) * 768 + k0 + sc], &As[(w * MF + j) * 512]);
    }
#pragma unroll
    for (int j = 0; j < 4; ++j) {
      int row = w * 32 + j * 8 + rsub;
      gload16(&Bt[(size_t)(n0 + row) * 768 + k0 + sc], &Bs[(w * 4 + j) * 512]);
    }
    __syncthreads();
    short8 a[MF][2], b[4][2];
#pragma unroll
    for (int h = 0; h < 2; ++h) {
#pragma unroll
      for (int mf = 0; mf < MF; ++mf) {
        int cw = ((h * 4 + lg) ^ (lr & 7)) * 8;
        a[mf][h] = *(const short8*)&As[(wm + mf * 16 + lr) * 64 + cw];
      }
#pragma unroll
      for (int nf = 0; nf < 4; ++nf) {
        int cw = ((h * 4 + lg) ^ (lr & 7)) * 8;
        b[nf][h] = *(const short8*)&Bs[(wn + nf * 16 + lr) * 64 + cw];
      }
    }
#pragma unroll
    for (int h = 0; h < 2; ++h)
#pragma unroll
      for (int mf = 0; mf < MF; ++mf)
#pragma unroll
        for (int nf = 0; nf < 4; ++nf)
          acc[mf][nf] = mfma_bf16(a[mf][h], b[nf][h], acc[mf][nf]);
  }

  if constexpr (MODE == 0) {
    int sec = (n0 >= 1536) ? 2 : (n0 >= 768 ? 1 : 0);
    int ncol0 = n0 - sec * 768;
    if (sec < 2) {
#pragma unroll
      for (int nf = 0; nf < 4; ++nf) {
        int nn = wn + nf * 16 + lr;
        float bv = bias[n0 + nn];
        int c = ncol0 + nn;
        int hh = c >> 6, d = c & 63;
#pragma unroll
        for (int mf = 0; mf < MF; ++mf)
#pragma unroll
          for (int rr = 0; rr < 4; ++rr) {
            int m = m0 + wm + mf * 16 + 4 * lg + rr;
            int bb = m >> 11, tt = m & 2047;
            int bh = bb * 12 + hh;
            float v = acc[mf][nf][rr] + bv;
            if (sec == 0) qb[((size_t)bh * T_ + tt) * 64 + d] = f2bf(v * QK_SCALE);
            else          kb[((size_t)bh * T_ + tt) * 64 + d] = f2bf(v);
          }
      }
    } else {
      // V^T: transpose in LDS (p5 key-permutation folded into column), coalesced rows out.
      __syncthreads();
#pragma unroll
      for (int nf = 0; nf < 4; ++nf) {
        int row = wn + nf * 16 + lr;
        float bv = bias[n0 + row];
        int swz = (row & 7) << 3;
#pragma unroll
        for (int mf = 0; mf < MF; ++mf) {
          int pcol0 = wm + (mf >> 1) * 32 + 8 * lg + 4 * (mf & 1);
          u32x2 pk;
          pk[0] = cvt_pk_bf16(acc[mf][nf][0] + bv, acc[mf][nf][1] + bv);
          pk[1] = cvt_pk_bf16(acc[mf][nf][2] + bv, acc[mf][nf][3] + bv);
          *(u32x2*)&S[row * MTILE + (pcol0 ^ swz)] = pk;
        }
      }
      __syncthreads();
      constexpr int CPT = MTILE / 2;
      int rowo = tid >> 1, half = tid & 1;
      int c = ncol0 + rowo;
      int d = c & 63, hh = c >> 6;
      int bh = (m0 >> 11) * 12 + hh;
      u16* dst = vpb + ((size_t)bh * 64 + d) * T_ + (m0 & 2047) + half * CPT;
      int swzo = (rowo & 7) << 3;
#pragma unroll
      for (int i = 0; i < CPT / 8; ++i) {
        int col = half * CPT + i * 8;
        uint4 v = *(const uint4*)&S[rowo * MTILE + (col ^ swzo)];
        *(uint4*)&dst[i * 8] = v;
      }
    }
  } else {
#pragma unroll
    for (int nf = 0; nf < 4; ++nf) {
      int n = n0 + wn + nf * 16 + lr;
      float bv = bias[n];
#pragma unroll
      for (int mf = 0; mf < MF; ++mf)
#pragma unroll
        for (int rr = 0; rr < 4; ++rr) {
          int m = m0 + wm + mf * 16 + 4 * lg + rr;
          out[(size_t)m * 768 + n] = acc[mf][nf][rr] + bv;
        }
    }
  }
}

// ---------------- flash attention (8 waves key-split, 2 tiles per barrier) ----------------
// Same per-tile math/addressing as R13/R14 (verified), but each barrier interval
// covers TWO 64-key tiles: 4 K bufs + 4 V bufs (pair-double-buffer), stage tiles
// tp+2/tp+3 while computing tp/tp+1. Critical block: 16 intervals (was 32).
// LDS 64 KB -> 2 blocks/CU, 16 waves/CU.

__global__ __launch_bounds__(512) void attn_kernel(const u16* __restrict__ Q,
                                                   const u16* __restrict__ K,
                                                   const u16* __restrict__ Vp,
                                                   u16* __restrict__ O) {
  __shared__ u16 sh[32768];  // K bufs 4x4096 [0..16384), V bufs 4x4096 [16384..32768)
  int tid = threadIdx.x;
  int w = tid >> 6, l = tid & 63, lg = l >> 4, lr = l & 15;
  int i = w >> 1, j = w & 1;
  int idx = blockIdx.x;
  int head = idx % 24;                 // 24 % 8 == 0: same head -> same XCD (L2 reuse)
  int qblk = 31 - idx / 24;            // big-work blocks dispatch first
  int b = head / 12, h = head % 12;
  int q0 = qblk * 64;
  int q0w = q0 + i * 16;               // this wave's 16 q-rows
  const u16* Qb = Q + (size_t)head * T_ * 64;
  const u16* Kb = K + (size_t)head * T_ * 64;
  const u16* Vb = Vp + (size_t)head * 64 * T_;

  short8 qf0 = *(const short8*)&Qb[(size_t)(q0w + lr) * 64 + 8 * lg];
  short8 qf1 = *(const short8*)&Qb[(size_t)(q0w + lr) * 64 + 32 + 8 * lg];

  f32x4 ao[4] = {};
  float lrow = 0.f;                    // per-lane partial (this wave's key half)
  int rsub = l >> 3;
  int scs = ((l & 7) ^ rsub) * 8;
  int row = w * 8 + rsub;              // staging row (same formula as R13)
  const int nt = qblk + 1;

  // prologue: stage tiles 0 and 1 into bufs 0,1
  gload16(&Kb[(size_t)row * 64 + scs], &sh[w * 512]);
  gload16(&Vb[(size_t)row * T_ + scs], &sh[16384 + w * 512]);
  if (nt > 1) {
    gload16(&Kb[(size_t)(64 + row) * 64 + scs], &sh[4096 + w * 512]);
    gload16(&Vb[(size_t)row * T_ + 64 + scs], &sh[16384 + 4096 + w * 512]);
  }
  __syncthreads();

  for (int tp = 0; tp < nt; tp += 2) {
    int p = (tp >> 1) & 1;
    // stage tiles tp+2, tp+3 into the other pair (bufs 2(p^1), 2(p^1)+1)
    if (tp + 2 < nt) {
      int base = ((p ^ 1) * 2) * 4096;
      gload16(&Kb[(size_t)((tp + 2) * 64 + row) * 64 + scs], &sh[base + w * 512]);
      gload16(&Vb[(size_t)row * T_ + (tp + 2) * 64 + scs], &sh[16384 + base + w * 512]);
    }
    if (tp + 3 < nt) {
      int base = ((p ^ 1) * 2 + 1) * 4096;
      gload16(&Kb[(size_t)((tp + 3) * 64 + row) * 64 + scs], &sh[base + w * 512]);
      gload16(&Vb[(size_t)row * T_ + (tp + 3) * 64 + scs], &sh[16384 + base + w * 512]);
    }
#pragma unroll
    for (int sub = 0; sub < 2; ++sub) {
      int t = tp + sub;
      if (t < nt) {
        int k0 = t * 64;
        if (k0 + 32 * j <= q0w + 15) {   // wave-uniform: skip all-masked key-half
          const u16* ks = sh + (p * 2 + sub) * 4096;
          const u16* vs = sh + 16384 + (p * 2 + sub) * 4096;
          short8 ka0[2], ka1[2], va[4];
#pragma unroll
          for (int g = 0; g < 2; ++g) {
            int kg = 2 * j + g;
            ka0[g] = *(const short8*)&ks[(kg * 16 + lr) * 64 + ((lg ^ (lr & 7)) * 8)];
            ka1[g] = *(const short8*)&ks[(kg * 16 + lr) * 64 + (((4 + lg) ^ (lr & 7)) * 8)];
          }
#pragma unroll
          for (int dt = 0; dt < 4; ++dt)
            va[dt] = *(const short8*)&vs[(dt * 16 + lr) * 64 + (((4 * j + lg) ^ (lr & 7)) * 8)];
          f32x4 sm[2];
          __builtin_amdgcn_s_setprio(1);
#pragma unroll
          for (int g = 0; g < 2; ++g) {
            f32x4 z = {};
            z = mfma_bf16(ka0[g], qf0, z);
            z = mfma_bf16(ka1[g], qf1, z);
            sm[g] = z;
          }
          __builtin_amdgcn_s_setprio(0);
          float sv[8];
          float ps = 0.f;
          bool needmask = (t == nt - 1) && (32 * j + 31 > 16 * i);
          if (needmask) {
            int qa = q0w + lr;
#pragma unroll
            for (int g = 0; g < 2; ++g)
#pragma unroll
              for (int rr = 0; rr < 4; ++rr) {
                int key = k0 + (2 * j + g) * 16 + 4 * lg + rr;
                float x = (key <= qa) ? sm[g][rr] : -1e30f;
                float pv = __builtin_amdgcn_exp2f(x);   // exp2(-1e30) = 0
                sv[g * 4 + rr] = pv;
                ps += pv;
              }
          } else {
#pragma unroll
            for (int g = 0; g < 2; ++g)
#pragma unroll
              for (int rr = 0; rr < 4; ++rr) {
                float pv = __builtin_amdgcn_exp2f(sm[g][rr]);
                sv[g * 4 + rr] = pv;
                ps += pv;
              }
          }
          lrow += ps;
          u32x4 uu;
          uu[0] = cvt_pk_bf16(sv[0], sv[1]);
          uu[1] = cvt_pk_bf16(sv[2], sv[3]);
          uu[2] = cvt_pk_bf16(sv[4], sv[5]);
          uu[3] = cvt_pk_bf16(sv[6], sv[7]);
          short8 pb = __builtin_bit_cast(short8, uu);
          __builtin_amdgcn_s_setprio(1);
#pragma unroll
          for (int dt = 0; dt < 4; ++dt)
            ao[dt] = mfma_bf16(va[dt], pb, ao[dt]);
          __builtin_amdgcn_s_setprio(0);
        }
      }
    }
    __syncthreads();
  }

  // reduce partial row-sums within wave (lanes {l, l^16, l^32, l^48} share q = lr)
  lrow += __shfl_xor(lrow, 16);
  lrow += __shfl_xor(lrow, 32);

  // merge key-half partials: j=1 writes (ao, lrow) to LDS; j=0 adds.
  float* aoL = (float*)sh;                    // [4][64][16] f32 = 16 KB
  float* lrL = (float*)(sh + 8192);           // [4][64] f32 = 1 KB
  if (j == 1) {
#pragma unroll
    for (int dt = 0; dt < 4; ++dt)
      *(f32x4*)&aoL[(i * 64 + l) * 16 + dt * 4] = ao[dt];
    lrL[i * 64 + l] = lrow;
  }
  __syncthreads();
  if (j == 0) {
#pragma unroll
    for (int dt = 0; dt < 4; ++dt)
      ao[dt] += *(const f32x4*)&aoL[(i * 64 + l) * 16 + dt * 4];
    lrow += lrL[i * 64 + l];
    // epilogue: normalize + transpose O^T(d,q) -> O(q,d) via per-i LDS region
    u16* ow = sh + 9216 + i * 1152;   // [16][72]
    float inv = 1.0f / lrow;
#pragma unroll
    for (int dt = 0; dt < 4; ++dt) {
      u32x2 pk;
      pk[0] = cvt_pk_bf16(ao[dt][0] * inv, ao[dt][1] * inv);
      pk[1] = cvt_pk_bf16(ao[dt][2] * inv, ao[dt][3] * inv);
      *(u32x2*)&ow[lr * 72 + dt * 16 + 4 * lg] = pk;
    }
    asm volatile("s_waitcnt lgkmcnt(0)" ::: "memory");  // wave-local write->read
    int r = l >> 2, hc = l & 3;
    const u16* srow = sh + 9216 + i * 1152 + r * 72 + hc * 16;
    u16* dst = O + ((size_t)(b * T_ + q0w + r)) * 768 + h * 64 + hc * 16;
    *(uint4*)&dst[0] = *(const uint4*)&srow[0];
    *(uint4*)&dst[8] = *(const uint4*)&srow[8];
  }
}

// ---------------- launch ----------------

extern "C" void kernel_launch(void* const* d_in, const int* in_sizes, int n_in,
                              void* d_out, int out_size, void* d_ws, size_t ws_size,
                              hipStream_t stream) {
  const float* x     = (const float*)d_in[0];
  const float* Wqkv  = (const float*)d_in[1];
  const float* bqkv  = (const float*)d_in[2];
  const float* Wproj = (const float*)d_in[3];
  const float* bproj = (const float*)d_in[4];
  float* out = (float*)d_out;
  char* ws = (char*)d_ws;
  u16* xb     = (u16*)(ws);                // 4096*768*2      = 6291456
  u16* wqkvT  = (u16*)(ws + 6291456);      // 2304*768*2      = 3538944
  u16* wprojT = (u16*)(ws + 9830400);      // 768*768*2       = 1179648
  u16* qb     = (u16*)(ws + 11010048);     // 24*2048*64*2    = 6291456
  u16* kb     = (u16*)(ws + 17301504);     // 6291456
  u16* vpb    = (u16*)(ws + 23592960);     // 6291456
  u16* ob     = (u16*)(ws + 29884416);     // 6291456  (total 36175872)

  prep_kernel<<<5376, 256, 0, stream>>>(x, Wqkv, Wproj, xb, wqkvT, wprojT);
  gemm_kernel<0, 64><<<dim3(18, 64), 256, 0, stream>>>(xb, wqkvT, bqkv, qb, kb, vpb, nullptr);
  attn_kernel<<<768, 512, 0, stream>>>(qb, kb, vpb, ob);
  gemm_kernel<1, 32><<<dim3(6, 128), 256, 0, stream>>>(ob, wprojT, bproj, nullptr, nullptr, nullptr, out);
}

// Round 16
// 71.594 us; speedup vs baseline: 1.7770x; 1.0330x over previous
//
#include <hip/hip_runtime.h>
#include <stdint.h>

typedef short short8 __attribute__((ext_vector_type(8)));
typedef short short4v __attribute__((ext_vector_type(4)));
typedef float f32x4 __attribute__((ext_vector_type(4)));
typedef unsigned int u32x2 __attribute__((ext_vector_type(2)));
typedef unsigned int u32x4 __attribute__((ext_vector_type(4)));
typedef unsigned short u16;
typedef unsigned int u32;

#define T_ 2048
#define QK_SCALE 0.180336878f   // 0.125 * log2(e): softmax in log2 domain

__device__ inline u16 f2bf(float f) {
  unsigned u = __builtin_bit_cast(unsigned, f);
  u += 0x7fffu + ((u >> 16) & 1u);   // RNE; inputs finite
  return (u16)(u >> 16);
}

__device__ inline u32 cvt_pk_bf16(float lo, float hi) {
  u32 r;
  asm("v_cvt_pk_bf16_f32 %0, %1, %2" : "=v"(r) : "v"(lo), "v"(hi));
  return r;
}

__device__ inline f32x4 mfma_bf16(short8 a, short8 b, f32x4 c) {
  return __builtin_amdgcn_mfma_f32_16x16x32_bf16(a, b, c, 0, 0, 0);
}

// async global->LDS, 16B per lane; lds base must be wave-uniform
__device__ inline void gload16(const u16* g, u16* l) {
  __builtin_amdgcn_global_load_lds(
      (const __attribute__((address_space(1))) void*)g,
      (__attribute__((address_space(3))) void*)l, 16, 0, 0);
}

// ---------------- fused prep: convert x + transpose-convert both weights ----------------

__device__ inline void tile_transpose(const float* __restrict__ W, u16* __restrict__ Wt,
                                      int R, int Ccols, int c0, int r0, int t,
                                      float (*tile)[33]) {
  int tr = t >> 3, tc = (t & 7) * 4;
  float4 v = *(const float4*)&W[(size_t)(r0 + tr) * Ccols + c0 + tc];
  tile[tr][tc + 0] = v.x; tile[tr][tc + 1] = v.y;
  tile[tr][tc + 2] = v.z; tile[tr][tc + 3] = v.w;
  __syncthreads();
  short4v o;
#pragma unroll
  for (int i = 0; i < 4; ++i) o[i] = (short)f2bf(tile[tc + i][tr]);
  *(short4v*)&Wt[(size_t)(c0 + tr) * R + r0 + tc] = o;
}

__global__ __launch_bounds__(256) void prep_kernel(const float* __restrict__ x,
                                                   const float* __restrict__ Wqkv,
                                                   const float* __restrict__ Wproj,
                                                   u16* __restrict__ xb,
                                                   u16* __restrict__ wqkvT,
                                                   u16* __restrict__ wprojT) {
  __shared__ float tile[32][33];
  int bid = blockIdx.x, t = threadIdx.x;
  if (bid < 3072) {
    int i = (bid * 256 + t) * 4;
    float4 v = *(const float4*)&x[i];
    short4v o;
    o[0] = (short)f2bf(v.x); o[1] = (short)f2bf(v.y);
    o[2] = (short)f2bf(v.z); o[3] = (short)f2bf(v.w);
    *(short4v*)&xb[i] = o;
  } else if (bid < 3072 + 1728) {
    int t2 = bid - 3072;
    tile_transpose(Wqkv, wqkvT, 768, 2304, (t2 % 72) * 32, (t2 / 72) * 32, t, tile);
  } else {
    int t3 = bid - 4800;
    tile_transpose(Wproj, wprojT, 768, 768, (t3 % 24) * 32, (t3 / 24) * 32, t, tile);
  }
}

// ---------------- MTILE x 128 GEMM, LDS double-buffered, 1 barrier/iter ----------------
// MODE 0 (MTILE=64): qkv epilogue; MODE 1 (MTILE=32): proj epilogue.
// Stage kt+1 into buf p^1 while computing kt from buf p; loads get the whole
// MFMA phase to land before the syncthreads drain (R15-verified pattern).

template <int MODE, int MTILE>
__global__ __launch_bounds__(256) void gemm_kernel(const u16* __restrict__ A,
                                                   const u16* __restrict__ Bt,
                                                   const float* __restrict__ bias,
                                                   u16* __restrict__ qb,
                                                   u16* __restrict__ kb,
                                                   u16* __restrict__ vpb,
                                                   float* __restrict__ out) {
  constexpr int MF = MTILE / 32;            // m-fragments per wave
  constexpr int ABUF = MTILE * 64;          // per-buffer A size (u16)
  __shared__ u16 S[2 * ABUF + 2 * 8192];    // As dbuf | Bs dbuf
  u16* As = S;
  u16* Bs = S + 2 * ABUF;
  int tid = threadIdx.x, w = tid >> 6, l = tid & 63, lg = l >> 4, lr = l & 15;
  int nwg = gridDim.x * gridDim.y;
  int hw = blockIdx.y * gridDim.x + blockIdx.x;
  int logical = (hw & 7) * (nwg >> 3) + (hw >> 3);
  int n0 = (logical % gridDim.x) * 128, m0 = (logical / gridDim.x) * MTILE;
  int wm = (w >> 1) * (MTILE / 2), wn = (w & 1) * 64;
  f32x4 acc[MF][4] = {};
  int rsub = l >> 3;
  int sc = ((l & 7) ^ rsub) * 8;

  // prologue: stage tile 0 into buf 0
#pragma unroll
  for (int j = 0; j < MF; ++j) {
    int row = w * (MTILE / 4) + j * 8 + rsub;
    gload16(&A[(size_t)(m0 + row) * 768 + sc], &As[(w * MF + j) * 512]);
  }
#pragma unroll
  for (int j = 0; j < 4; ++j) {
    int row = w * 32 + j * 8 + rsub;
    gload16(&Bt[(size_t)(n0 + row) * 768 + sc], &Bs[(w * 4 + j) * 512]);
  }
  __syncthreads();

  for (int kt = 0; kt < 12; ++kt) {
    int p = kt & 1;
    if (kt + 1 < 12) {
      int k1 = (kt + 1) * 64;
#pragma unroll
      for (int j = 0; j < MF; ++j) {
        int row = w * (MTILE / 4) + j * 8 + rsub;
        gload16(&A[(size_t)(m0 + row) * 768 + k1 + sc], &As[(p ^ 1) * ABUF + (w * MF + j) * 512]);
      }
#pragma unroll
      for (int j = 0; j < 4; ++j) {
        int row = w * 32 + j * 8 + rsub;
        gload16(&Bt[(size_t)(n0 + row) * 768 + k1 + sc], &Bs[(p ^ 1) * 8192 + (w * 4 + j) * 512]);
      }
    }
    const u16* Ap = As + p * ABUF;
    const u16* Bp = Bs + p * 8192;
    short8 a[MF][2], b[4][2];
#pragma unroll
    for (int h = 0; h < 2; ++h) {
#pragma unroll
      for (int mf = 0; mf < MF; ++mf) {
        int cw = ((h * 4 + lg) ^ (lr & 7)) * 8;
        a[mf][h] = *(const short8*)&Ap[(wm + mf * 16 + lr) * 64 + cw];
      }
#pragma unroll
      for (int nf = 0; nf < 4; ++nf) {
        int cw = ((h * 4 + lg) ^ (lr & 7)) * 8;
        b[nf][h] = *(const short8*)&Bp[(wn + nf * 16 + lr) * 64 + cw];
      }
    }
#pragma unroll
    for (int h = 0; h < 2; ++h)
#pragma unroll
      for (int mf = 0; mf < MF; ++mf)
#pragma unroll
        for (int nf = 0; nf < 4; ++nf)
          acc[mf][nf] = mfma_bf16(a[mf][h], b[nf][h], acc[mf][nf]);
    __syncthreads();
  }

  if constexpr (MODE == 0) {
    int sec = (n0 >= 1536) ? 2 : (n0 >= 768 ? 1 : 0);
    int ncol0 = n0 - sec * 768;
    if (sec < 2) {
#pragma unroll
      for (int nf = 0; nf < 4; ++nf) {
        int nn = wn + nf * 16 + lr;
        float bv = bias[n0 + nn];
        int c = ncol0 + nn;
        int hh = c >> 6, d = c & 63;
#pragma unroll
        for (int mf = 0; mf < MF; ++mf)
#pragma unroll
          for (int rr = 0; rr < 4; ++rr) {
            int m = m0 + wm + mf * 16 + 4 * lg + rr;
            int bb = m >> 11, tt = m & 2047;
            int bh = bb * 12 + hh;
            float v = acc[mf][nf][rr] + bv;
            if (sec == 0) qb[((size_t)bh * T_ + tt) * 64 + d] = f2bf(v * QK_SCALE);
            else          kb[((size_t)bh * T_ + tt) * 64 + d] = f2bf(v);
          }
      }
    } else {
      // V^T: transpose in LDS (p5 key-permutation folded into column), coalesced rows out.
      // (reuses S[0..8192): barrier-protected, loop is done with LDS)
#pragma unroll
      for (int nf = 0; nf < 4; ++nf) {
        int row = wn + nf * 16 + lr;
        float bv = bias[n0 + row];
        int swz = (row & 7) << 3;
#pragma unroll
        for (int mf = 0; mf < MF; ++mf) {
          int pcol0 = wm + (mf >> 1) * 32 + 8 * lg + 4 * (mf & 1);
          u32x2 pk;
          pk[0] = cvt_pk_bf16(acc[mf][nf][0] + bv, acc[mf][nf][1] + bv);
          pk[1] = cvt_pk_bf16(acc[mf][nf][2] + bv, acc[mf][nf][3] + bv);
          *(u32x2*)&S[row * MTILE + (pcol0 ^ swz)] = pk;
        }
      }
      __syncthreads();
      constexpr int CPT = MTILE / 2;
      int rowo = tid >> 1, half = tid & 1;
      int c = ncol0 + rowo;
      int d = c & 63, hh = c >> 6;
      int bh = (m0 >> 11) * 12 + hh;
      u16* dst = vpb + ((size_t)bh * 64 + d) * T_ + (m0 & 2047) + half * CPT;
      int swzo = (rowo & 7) << 3;
#pragma unroll
      for (int i = 0; i < CPT / 8; ++i) {
        int col = half * CPT + i * 8;
        uint4 v = *(const uint4*)&S[rowo * MTILE + (col ^ swzo)];
        *(uint4*)&dst[i * 8] = v;
      }
    }
  } else {
#pragma unroll
    for (int nf = 0; nf < 4; ++nf) {
      int n = n0 + wn + nf * 16 + lr;
      float bv = bias[n];
#pragma unroll
      for (int mf = 0; mf < MF; ++mf)
#pragma unroll
        for (int rr = 0; rr < 4; ++rr) {
          int m = m0 + wm + mf * 16 + 4 * lg + rr;
          out[(size_t)m * 768 + n] = acc[mf][nf][rr] + bv;
        }
    }
  }
}

// ---------------- flash attention (8 waves key-split, 2 tiles per barrier) ----------------
// Identical to R15 (verified 74.0 us total).

__global__ __launch_bounds__(512) void attn_kernel(const u16* __restrict__ Q,
                                                   const u16* __restrict__ K,
                                                   const u16* __restrict__ Vp,
                                                   u16* __restrict__ O) {
  __shared__ u16 sh[32768];  // K bufs 4x4096 [0..16384), V bufs 4x4096 [16384..32768)
  int tid = threadIdx.x;
  int w = tid >> 6, l = tid & 63, lg = l >> 4, lr = l & 15;
  int i = w >> 1, j = w & 1;
  int idx = blockIdx.x;
  int head = idx % 24;                 // 24 % 8 == 0: same head -> same XCD (L2 reuse)
  int qblk = 31 - idx / 24;            // big-work blocks dispatch first
  int b = head / 12, h = head % 12;
  int q0 = qblk * 64;
  int q0w = q0 + i * 16;               // this wave's 16 q-rows
  const u16* Qb = Q + (size_t)head * T_ * 64;
  const u16* Kb = K + (size_t)head * T_ * 64;
  const u16* Vb = Vp + (size_t)head * 64 * T_;

  short8 qf0 = *(const short8*)&Qb[(size_t)(q0w + lr) * 64 + 8 * lg];
  short8 qf1 = *(const short8*)&Qb[(size_t)(q0w + lr) * 64 + 32 + 8 * lg];

  f32x4 ao[4] = {};
  float lrow = 0.f;                    // per-lane partial (this wave's key half)
  int rsub = l >> 3;
  int scs = ((l & 7) ^ rsub) * 8;
  int row = w * 8 + rsub;              // staging row
  const int nt = qblk + 1;

  // prologue: stage tiles 0 and 1 into bufs 0,1
  gload16(&Kb[(size_t)row * 64 + scs], &sh[w * 512]);
  gload16(&Vb[(size_t)row * T_ + scs], &sh[16384 + w * 512]);
  if (nt > 1) {
    gload16(&Kb[(size_t)(64 + row) * 64 + scs], &sh[4096 + w * 512]);
    gload16(&Vb[(size_t)row * T_ + 64 + scs], &sh[16384 + 4096 + w * 512]);
  }
  __syncthreads();

  for (int tp = 0; tp < nt; tp += 2) {
    int p = (tp >> 1) & 1;
    if (tp + 2 < nt) {
      int base = ((p ^ 1) * 2) * 4096;
      gload16(&Kb[(size_t)((tp + 2) * 64 + row) * 64 + scs], &sh[base + w * 512]);
      gload16(&Vb[(size_t)row * T_ + (tp + 2) * 64 + scs], &sh[16384 + base + w * 512]);
    }
    if (tp + 3 < nt) {
      int base = ((p ^ 1) * 2 + 1) * 4096;
      gload16(&Kb[(size_t)((tp + 3) * 64 + row) * 64 + scs], &sh[base + w * 512]);
      gload16(&Vb[(size_t)row * T_ + (tp + 3) * 64 + scs], &sh[16384 + base + w * 512]);
    }
#pragma unroll
    for (int sub = 0; sub < 2; ++sub) {
      int t = tp + sub;
      if (t < nt) {
        int k0 = t * 64;
        if (k0 + 32 * j <= q0w + 15) {   // wave-uniform: skip all-masked key-half
          const u16* ks = sh + (p * 2 + sub) * 4096;
          const u16* vs = sh + 16384 + (p * 2 + sub) * 4096;
          short8 ka0[2], ka1[2], va[4];
#pragma unroll
          for (int g = 0; g < 2; ++g) {
            int kg = 2 * j + g;
            ka0[g] = *(const short8*)&ks[(kg * 16 + lr) * 64 + ((lg ^ (lr & 7)) * 8)];
            ka1[g] = *(const short8*)&ks[(kg * 16 + lr) * 64 + (((4 + lg) ^ (lr & 7)) * 8)];
          }
#pragma unroll
          for (int dt = 0; dt < 4; ++dt)
            va[dt] = *(const short8*)&vs[(dt * 16 + lr) * 64 + (((4 * j + lg) ^ (lr & 7)) * 8)];
          f32x4 sm[2];
          __builtin_amdgcn_s_setprio(1);
#pragma unroll
          for (int g = 0; g < 2; ++g) {
            f32x4 z = {};
            z = mfma_bf16(ka0[g], qf0, z);
            z = mfma_bf16(ka1[g], qf1, z);
            sm[g] = z;
          }
          __builtin_amdgcn_s_setprio(0);
          float sv[8];
          float ps = 0.f;
          bool needmask = (t == nt - 1) && (32 * j + 31 > 16 * i);
          if (needmask) {
            int qa = q0w + lr;
#pragma unroll
            for (int g = 0; g < 2; ++g)
#pragma unroll
              for (int rr = 0; rr < 4; ++rr) {
                int key = k0 + (2 * j + g) * 16 + 4 * lg + rr;
                float x = (key <= qa) ? sm[g][rr] : -1e30f;
                float pv = __builtin_amdgcn_exp2f(x);   // exp2(-1e30) = 0
                sv[g * 4 + rr] = pv;
                ps += pv;
              }
          } else {
#pragma unroll
            for (int g = 0; g < 2; ++g)
#pragma unroll
              for (int rr = 0; rr < 4; ++rr) {
                float pv = __builtin_amdgcn_exp2f(sm[g][rr]);
                sv[g * 4 + rr] = pv;
                ps += pv;
              }
          }
          lrow += ps;
          u32x4 uu;
          uu[0] = cvt_pk_bf16(sv[0], sv[1]);
          uu[1] = cvt_pk_bf16(sv[2], sv[3]);
          uu[2] = cvt_pk_bf16(sv[4], sv[5]);
          uu[3] = cvt_pk_bf16(sv[6], sv[7]);
          short8 pb = __builtin_bit_cast(short8, uu);
          __builtin_amdgcn_s_setprio(1);
#pragma unroll
          for (int dt = 0; dt < 4; ++dt)
            ao[dt] = mfma_bf16(va[dt], pb, ao[dt]);
          __builtin_amdgcn_s_setprio(0);
        }
      }
    }
    __syncthreads();
  }

  // reduce partial row-sums within wave (lanes {l, l^16, l^32, l^48} share q = lr)
  lrow += __shfl_xor(lrow, 16);
  lrow += __shfl_xor(lrow, 32);

  // merge key-half partials: j=1 writes (ao, lrow) to LDS; j=0 adds.
  float* aoL = (float*)sh;                    // [4][64][16] f32 = 16 KB
  float* lrL = (float*)(sh + 8192);           // [4][64] f32 = 1 KB
  if (j == 1) {
#pragma unroll
    for (int dt = 0; dt < 4; ++dt)
      *(f32x4*)&aoL[(i * 64 + l) * 16 + dt * 4] = ao[dt];
    lrL[i * 64 + l] = lrow;
  }
  __syncthreads();
  if (j == 0) {
#pragma unroll
    for (int dt = 0; dt < 4; ++dt)
      ao[dt] += *(const f32x4*)&aoL[(i * 64 + l) * 16 + dt * 4];
    lrow += lrL[i * 64 + l];
    // epilogue: normalize + transpose O^T(d,q) -> O(q,d) via per-i LDS region
    u16* ow = sh + 9216 + i * 1152;   // [16][72]
    float inv = 1.0f / lrow;
#pragma unroll
    for (int dt = 0; dt < 4; ++dt) {
      u32x2 pk;
      pk[0] = cvt_pk_bf16(ao[dt][0] * inv, ao[dt][1] * inv);
      pk[1] = cvt_pk_bf16(ao[dt][2] * inv, ao[dt][3] * inv);
      *(u32x2*)&ow[lr * 72 + dt * 16 + 4 * lg] = pk;
    }
    asm volatile("s_waitcnt lgkmcnt(0)" ::: "memory");  // wave-local write->read
    int r = l >> 2, hc = l & 3;
    const u16* srow = sh + 9216 + i * 1152 + r * 72 + hc * 16;
    u16* dst = O + ((size_t)(b * T_ + q0w + r)) * 768 + h * 64 + hc * 16;
    *(uint4*)&dst[0] = *(const uint4*)&srow[0];
    *(uint4*)&dst[8] = *(const uint4*)&srow[8];
  }
}

// ---------------- launch ----------------

extern "C" void kernel_launch(void* const* d_in, const int* in_sizes, int n_in,
                              void* d_out, int out_size, void* d_ws, size_t ws_size,
                              hipStream_t stream) {
  const float* x     = (const float*)d_in[0];
  const float* Wqkv  = (const float*)d_in[1];
  const float* bqkv  = (const float*)d_in[2];
  const float* Wproj = (const float*)d_in[3];
  const float* bproj = (const float*)d_in[4];
  float* out = (float*)d_out;
  char* ws = (char*)d_ws;
  u16* xb     = (u16*)(ws);                // 4096*768*2      = 6291456
  u16* wqkvT  = (u16*)(ws + 6291456);      // 2304*768*2      = 3538944
  u16* wprojT = (u16*)(ws + 9830400);      // 768*768*2       = 1179648
  u16* qb     = (u16*)(ws + 11010048);     // 24*2048*64*2    = 6291456
  u16* kb     = (u16*)(ws + 17301504);     // 6291456
  u16* vpb    = (u16*)(ws + 23592960);     // 6291456
  u16* ob     = (u16*)(ws + 29884416);     // 6291456  (total 36175872)

  prep_kernel<<<5376, 256, 0, stream>>>(x, Wqkv, Wproj, xb, wqkvT, wprojT);
  gemm_kernel<0, 64><<<dim3(18, 64), 256, 0, stream>>>(xb, wqkvT, bqkv, qb, kb, vpb, nullptr);
  attn_kernel<<<768, 512, 0, stream>>>(qb, kb, vpb, ob);
  gemm_kernel<1, 32><<<dim3(6, 128), 256, 0, stream>>>(ob, wprojT, bproj, nullptr, nullptr, nullptr, out);
}